// Round 1
// baseline (1285.988 us; speedup 1.0000x reference)
//
#include <hip/hip_runtime.h>

#define N_NODES 50000
#define N_EDGES 800000
#define N_GRAPHS 256
#define F 100  // hidden dim

// ---------------- CSR build (counting sort by dst, rebuilt every call) ----------------

__global__ void hist_kernel(const int* __restrict__ dst, int* __restrict__ cnt, int E) {
  int e = blockIdx.x * blockDim.x + threadIdx.x;
  if (e < E) atomicAdd(&cnt[dst[e]], 1);
}

__global__ void scan_kernel(const int* __restrict__ cnt, int* __restrict__ offs,
                            int* __restrict__ cursor, int n) {
  __shared__ int part[1024];
  int t = threadIdx.x;
  const int CH = 49;  // 1024*49 = 50176 >= 50000
  int b0 = t * CH;
  int b1 = b0 + CH; if (b1 > n) b1 = n;
  int s = 0;
  for (int i = b0; i < b1; ++i) s += cnt[i];
  part[t] = s;
  __syncthreads();
  for (int off = 1; off < 1024; off <<= 1) {
    int v = (t >= off) ? part[t - off] : 0;
    __syncthreads();
    part[t] += v;
    __syncthreads();
  }
  int run = part[t] - s;  // exclusive prefix of this thread's chunk
  for (int i = b0; i < b1; ++i) {
    offs[i] = run; cursor[i] = run; run += cnt[i];
  }
  if (t == 1023) offs[n] = run;  // total = E
}

__global__ void fill_kernel(const int* __restrict__ src, const int* __restrict__ dst,
                            int* __restrict__ cursor, int* __restrict__ csr_src, int E) {
  int e = blockIdx.x * blockDim.x + threadIdx.x;
  if (e < E) {
    int p = atomicAdd(&cursor[dst[e]], 1);
    csr_src[p] = src[e];
  }
}

// ---------------- fused conv matmul: Zrel = relu?(H)@Wrel.T ; Zroot = relu?(H)@Wroot.T + b --------
// Tile: 64 nodes x 200 out-features per block, 256 threads as 16x16.
// Thread (ty,tx): nodes ty+16a (a<4), feats tx+16b (b<13, masked at m>=200).

constexpr int MM_BN = 64;
constexpr int KC = 16;
constexpr int LSTR = 20;  // LDS row stride (pad 16->20: float4-aligned, <=2-way bank alias = free)

template <bool RELU_IN>
__global__ __launch_bounds__(256) void conv_mm(
    const float* __restrict__ H, const float* __restrict__ Wrel,
    const float* __restrict__ Wroot, const float* __restrict__ bias,
    float* __restrict__ Zrel, float* __restrict__ Zroot, int N, int K) {
  __shared__ float hs[MM_BN * LSTR];   // 5.1 KB
  __shared__ float ws[208 * LSTR];     // 16.6 KB (rows 200..207 never written, reads masked)
  int tid = threadIdx.x;
  int tx = tid & 15, ty = tid >> 4;
  int n0 = blockIdx.x * MM_BN;
  float acc[4][13];
#pragma unroll
  for (int a = 0; a < 4; ++a)
#pragma unroll
    for (int b = 0; b < 13; ++b) acc[a][b] = 0.f;

  for (int k0 = 0; k0 < K; k0 += KC) {
    int kc = K - k0; if (kc > KC) kc = KC;  // 16, or 4 on the K=100 tail
    int nf4 = kc >> 2;                      // 4 or 1 float4s per row
    // stage H tile (zero-fill OOB rows; relu-on-load for hidden layers)
    for (int i = tid; i < MM_BN * nf4; i += 256) {
      int r = (nf4 == 4) ? (i >> 2) : i;
      int c = (nf4 == 4) ? (i & 3) : 0;
      int n = n0 + r;
      float4 v = make_float4(0.f, 0.f, 0.f, 0.f);
      if (n < N) v = *(const float4*)(H + (size_t)n * K + k0 + c * 4);
      if (RELU_IN) {
        v.x = fmaxf(v.x, 0.f); v.y = fmaxf(v.y, 0.f);
        v.z = fmaxf(v.z, 0.f); v.w = fmaxf(v.w, 0.f);
      }
      float* p = &hs[r * LSTR + c * 4];
      p[0] = v.x; p[1] = v.y; p[2] = v.z; p[3] = v.w;
    }
    // stage W tile: rows 0..99 = Wrel, 100..199 = Wroot
    for (int i = tid; i < 200 * nf4; i += 256) {
      int r = (nf4 == 4) ? (i >> 2) : i;
      int c = (nf4 == 4) ? (i & 3) : 0;
      const float* wp = (r < 100) ? (Wrel + (size_t)r * K) : (Wroot + (size_t)(r - 100) * K);
      float4 v = *(const float4*)(wp + k0 + c * 4);
      float* p = &ws[r * LSTR + c * 4];
      p[0] = v.x; p[1] = v.y; p[2] = v.z; p[3] = v.w;
    }
    __syncthreads();
    for (int kk = 0; kk < nf4; ++kk) {
      int k = kk * 4;
      float4 hv[4];
#pragma unroll
      for (int a = 0; a < 4; ++a) hv[a] = *(const float4*)&hs[(ty + 16 * a) * LSTR + k];
#pragma unroll
      for (int b = 0; b < 13; ++b) {
        float4 wv = *(const float4*)&ws[(tx + 16 * b) * LSTR + k];
#pragma unroll
        for (int a = 0; a < 4; ++a) {
          acc[a][b] += hv[a].x * wv.x;
          acc[a][b] += hv[a].y * wv.y;
          acc[a][b] += hv[a].z * wv.z;
          acc[a][b] += hv[a].w * wv.w;
        }
      }
    }
    __syncthreads();
  }
#pragma unroll
  for (int a = 0; a < 4; ++a) {
    int n = n0 + ty + 16 * a;
    if (n >= N) continue;
#pragma unroll
    for (int b = 0; b < 13; ++b) {
      int m = tx + 16 * b;
      if (m < 100) Zrel[(size_t)n * F + m] = acc[a][b];
      else if (m < 200) Zroot[(size_t)n * F + (m - 100)] = acc[a][b] + bias[m - 100];
    }
  }
}

// ---------------- per-node gather: Hout[i] = Zroot[i] + sum_{e in CSR[i]} Zrel[src_e] ------------
// Pre-relu stored; relu applied by the next consumer on load.

__global__ void gather_kernel(const float* __restrict__ Zrel, const float* __restrict__ Zroot,
                              const int* __restrict__ offs, const int* __restrict__ csr_src,
                              float* __restrict__ Hout) {
  int node = blockIdx.x;
  int f = threadIdx.x;
  if (f >= F) return;
  int s = offs[node], e = offs[node + 1];  // uniform -> scalar loads
  float acc = Zroot[(size_t)node * F + f];
  for (int j = s; j < e; ++j) {
    int sn = csr_src[j];  // uniform
    acc += Zrel[(size_t)sn * F + f];
  }
  Hout[(size_t)node * F + f] = acc;
}

// ---------------- global mean pool (batch sorted -> binary-search boundaries) --------------------

__global__ void pool_kernel(const float* __restrict__ Hl, const int* __restrict__ batch,
                            float* __restrict__ pooled) {
  int g = blockIdx.x;
  int f = threadIdx.x;
  int lo = 0, hi = N_NODES;
  while (lo < hi) { int mid = (lo + hi) >> 1; if (batch[mid] < g) lo = mid + 1; else hi = mid; }
  int s = lo;
  hi = N_NODES;
  while (lo < hi) { int mid = (lo + hi) >> 1; if (batch[mid] <= g) lo = mid + 1; else hi = mid; }
  int e = lo;
  if (f >= F) return;
  float acc = 0.f;
  for (int n = s; n < e; ++n) acc += fmaxf(Hl[(size_t)n * F + f], 0.f);
  int cnt = e - s;
  float d = (cnt > 0) ? (float)cnt : 1.f;
  pooled[(size_t)g * F + f] = acc / d;
}

// ---------------- fused 3-layer MLP head, one block per graph -----------------------------------

__global__ void mlp_kernel(const float* __restrict__ pooled,
                           const float* __restrict__ lw1, const float* __restrict__ lb1,
                           const float* __restrict__ lw2, const float* __restrict__ lb2,
                           const float* __restrict__ lw3, const float* __restrict__ lb3,
                           float* __restrict__ out) {
  int g = blockIdx.x;
  int t = threadIdx.x;
  __shared__ float r0[F], r1[F], r2[F];
  if (t < F) r0[t] = pooled[(size_t)g * F + t];
  __syncthreads();
  if (t < F) {
    float s = lb1[t];
    for (int k = 0; k < F; ++k) s += r0[k] * lw1[t * F + k];
    r1[t] = fmaxf(s, 0.f);
  }
  __syncthreads();
  if (t < F) {
    float s = lb2[t];
    for (int k = 0; k < F; ++k) s += r1[k] * lw2[t * F + k];
    r2[t] = fmaxf(s, 0.f);
  }
  __syncthreads();
  if (t < 29) {
    float s = lb3[t];
    for (int k = 0; k < F; ++k) s += r2[k] * lw3[t * F + k];
    out[g * 29 + t] = s;
  }
}

// ---------------- launch ------------------------------------------------------------------------

extern "C" void kernel_launch(void* const* d_in, const int* in_sizes, int n_in,
                              void* d_out, int out_size, void* d_ws, size_t ws_size,
                              hipStream_t stream) {
  const float* x       = (const float*)d_in[0];
  const int*   ei      = (const int*)d_in[1];
  const int*   batch   = (const int*)d_in[2];
  const float* w1_rel  = (const float*)d_in[3];
  const float* w1_root = (const float*)d_in[4];
  const float* b1      = (const float*)d_in[5];
  const float* w_rel   = (const float*)d_in[6];
  const float* w_root  = (const float*)d_in[7];
  const float* bvec    = (const float*)d_in[8];
  const float* lw1     = (const float*)d_in[9];
  const float* lb1     = (const float*)d_in[10];
  const float* lw2     = (const float*)d_in[11];
  const float* lb2     = (const float*)d_in[12];
  const float* lw3     = (const float*)d_in[13];
  const float* lb3     = (const float*)d_in[14];
  float* out = (float*)d_out;

  // workspace layout (~64 MB total)
  char* ws = (char*)d_ws;
  const size_t SZ_H = (size_t)N_NODES * F * sizeof(float);  // 20 MB
  float* bufH   = (float*)(ws);
  float* bufZr  = (float*)(ws + SZ_H);
  float* bufZo  = (float*)(ws + 2 * SZ_H);
  float* pooled = (float*)(ws + 3 * SZ_H);                       // 102.4 KB
  int*   cnt    = (int*)(ws + 3 * SZ_H + (size_t)128 * 1024);
  int*   offs   = cnt + 50176;
  int*   cursor = offs + 50176;
  int*   csr    = cursor + 50176;                                // 3.2 MB

  const int E = N_EDGES;
  const int* srcv = ei;
  const int* dstv = ei + E;

  // CSR build
  hipMemsetAsync(cnt, 0, (N_NODES + 1) * sizeof(int), stream);
  hist_kernel<<<(E + 255) / 256, 256, 0, stream>>>(dstv, cnt, E);
  scan_kernel<<<1, 1024, 0, stream>>>(cnt, offs, cursor, N_NODES);
  fill_kernel<<<(E + 255) / 256, 256, 0, stream>>>(srcv, dstv, cursor, csr, E);

  int mmgrid = (N_NODES + MM_BN - 1) / MM_BN;  // 782
  // layer 1 (K=336, raw x input)
  conv_mm<false><<<mmgrid, 256, 0, stream>>>(x, w1_rel, w1_root, b1, bufZr, bufZo, N_NODES, 336);
  gather_kernel<<<N_NODES, 128, 0, stream>>>(bufZr, bufZo, offs, csr, bufH);
  // layers 2..5 (K=100, relu-on-load)
  for (int l = 0; l < 4; ++l) {
    conv_mm<true><<<mmgrid, 256, 0, stream>>>(bufH, w_rel + (size_t)l * F * F,
                                              w_root + (size_t)l * F * F,
                                              bvec + (size_t)l * F, bufZr, bufZo, N_NODES, 100);
    gather_kernel<<<N_NODES, 128, 0, stream>>>(bufZr, bufZo, offs, csr, bufH);
  }
  pool_kernel<<<N_GRAPHS, 128, 0, stream>>>(bufH, batch, pooled);
  mlp_kernel<<<N_GRAPHS, 128, 0, stream>>>(pooled, lw1, lb1, lw2, lb2, lw3, lb3, out);
}

// Round 2
// 746.782 us; speedup vs baseline: 1.7220x; 1.7220x over previous
//
#include <hip/hip_runtime.h>

#define N_NODES 50000
#define N_EDGES 800000
#define N_GRAPHS 256
#define F 100  // hidden dim

typedef __attribute__((ext_vector_type(8))) short bf16x8;
typedef __attribute__((ext_vector_type(4))) float f32x4;
typedef unsigned short ushort_t;
typedef unsigned int uint_t;

__device__ inline ushort_t f2bf(float f) {  // RNE float->bf16
  uint_t u = __float_as_uint(f);
  uint_t r = (u + 0x7fffu + ((u >> 16) & 1u)) >> 16;
  return (ushort_t)r;
}

// ---------------- CSR build (counting sort by dst, rebuilt every call) ----------------

__global__ void hist_kernel(const int* __restrict__ dst, int* __restrict__ cnt, int E) {
  int e = blockIdx.x * blockDim.x + threadIdx.x;
  if (e < E) atomicAdd(&cnt[dst[e]], 1);
}

__global__ void scan_kernel(const int* __restrict__ cnt, int* __restrict__ offs,
                            int* __restrict__ cursor, int n) {
  __shared__ int part[1024];
  int t = threadIdx.x;
  const int CH = 49;
  int b0 = t * CH;
  int b1 = b0 + CH; if (b1 > n) b1 = n;
  int s = 0;
  for (int i = b0; i < b1; ++i) s += cnt[i];
  part[t] = s;
  __syncthreads();
  for (int off = 1; off < 1024; off <<= 1) {
    int v = (t >= off) ? part[t - off] : 0;
    __syncthreads();
    part[t] += v;
    __syncthreads();
  }
  int run = part[t] - s;
  for (int i = b0; i < b1; ++i) {
    offs[i] = run; cursor[i] = run; run += cnt[i];
  }
  if (t == 1023) offs[n] = run;
}

__global__ void fill_kernel(const int* __restrict__ src, const int* __restrict__ dst,
                            int* __restrict__ cursor, int* __restrict__ csr_src, int E) {
  int e = blockIdx.x * blockDim.x + threadIdx.x;
  if (e < E) {
    int p = atomicAdd(&cursor[dst[e]], 1);
    csr_src[p] = src[e];
  }
}

// ---------------- weight packing: [208][Kp] bf16, zero-padded ----------------

__global__ void pack_w1_kernel(const float* __restrict__ w1_rel, const float* __restrict__ w1_root,
                               ushort_t* __restrict__ Wp1) {
  int row = blockIdx.x;  // 208
  for (int k = threadIdx.x; k < 352; k += 128) {
    float v = 0.f;
    if (k < 336) {
      if (row < 100) v = w1_rel[row * 336 + k];
      else if (row < 200) v = w1_root[(row - 100) * 336 + k];
    }
    Wp1[(size_t)row * 352 + k] = f2bf(v);
  }
}

__global__ void pack_w_kernel(const float* __restrict__ w_rel, const float* __restrict__ w_root,
                              ushort_t* __restrict__ Wp) {
  int row = blockIdx.x;  // 208
  int l = blockIdx.y;    // 4
  int k = threadIdx.x;   // 128
  float v = 0.f;
  if (k < 100) {
    if (row < 100) v = w_rel[((size_t)l * 100 + row) * 100 + k];
    else if (row < 200) v = w_root[((size_t)l * 100 + row - 100) * 100 + k];
  }
  Wp[((size_t)l * 208 + row) * 128 + k] = f2bf(v);
}

// ---------------- MFMA conv: Zrel = A@Wrel.T (bf16), Zroot = A@Wroot.T + b ----------------
// Block: 128 threads = 2 waves. Block tile: 64 nodes x 208 feats.
// Wave w covers rows [w*32, w*32+32) as two 16-row m-tiles; 13 n-tiles of 16.
// mfma_f32_16x16x32_bf16 layouts (m89/m91-verified):
//   A: lane holds A[m=lane&15][k=(lane>>4)*8+j]; B: B[k=(lane>>4)*8+j][n=lane&15]
//   D: lane,reg -> D[m=(lane>>4)*4+reg][n=lane&15]

template <bool AF32>
__global__ __launch_bounds__(128) void conv_mfma(
    const void* __restrict__ Aptr, const ushort_t* __restrict__ Wp,
    const float* __restrict__ bias,
    ushort_t* __restrict__ Zrel, ushort_t* __restrict__ Zroot, int Kp) {
  __shared__ short alds[4 * 64 * 8];    // [q][row64][8]  4 KB
  __shared__ short blds[4 * 208 * 8];   // [q][row208][8] 13.3 KB
  __shared__ float bias_s[100];

  int tid = threadIdx.x;
  int n0 = blockIdx.x * 64;
  if (tid < 100) bias_s[tid] = bias[tid];

  f32x4 acc0[13], acc1[13];
#pragma unroll
  for (int b = 0; b < 13; ++b) { acc0[b] = (f32x4)0.f; acc1[b] = (f32x4)0.f; }

  int w = tid >> 6, lane = tid & 63, q = lane >> 4, m16 = lane & 15;

  for (int k0 = 0; k0 < Kp; k0 += 32) {
    // stage A: 64 rows x 4 quads of 8 bf16
#pragma unroll
    for (int i = tid; i < 256; i += 128) {
      int nl = i >> 2, qq = i & 3;
      int node = n0 + nl;
      bf16x8 val = (bf16x8)0;
      if (AF32) {
        int k = k0 + qq * 8;
        if (node < N_NODES && k < 336) {
          const float* p = (const float*)Aptr + (size_t)node * 336 + k;
          float4 f0 = *(const float4*)p;
          float4 f1 = *(const float4*)(p + 4);
          val[0] = (short)f2bf(f0.x); val[1] = (short)f2bf(f0.y);
          val[2] = (short)f2bf(f0.z); val[3] = (short)f2bf(f0.w);
          val[4] = (short)f2bf(f1.x); val[5] = (short)f2bf(f1.y);
          val[6] = (short)f2bf(f1.z); val[7] = (short)f2bf(f1.w);
        }
      } else {
        if (node < N_NODES)
          val = *(const bf16x8*)((const short*)Aptr + (size_t)node * 128 + k0 + qq * 8);
      }
      *(bf16x8*)&alds[(qq * 64 + nl) * 8] = val;
    }
    // stage B: 208 rows x 4 quads
    for (int i = tid; i < 832; i += 128) {
      int n = i >> 2, qq = i & 3;
      *(bf16x8*)&blds[(qq * 208 + n) * 8] =
          *(const bf16x8*)((const short*)Wp + (size_t)n * Kp + k0 + qq * 8);
    }
    __syncthreads();
    bf16x8 a0 = *(const bf16x8*)&alds[(q * 64 + w * 32 + m16) * 8];
    bf16x8 a1 = *(const bf16x8*)&alds[(q * 64 + w * 32 + 16 + m16) * 8];
#pragma unroll
    for (int b = 0; b < 13; ++b) {
      bf16x8 bf = *(const bf16x8*)&blds[(q * 208 + b * 16 + m16) * 8];
      acc0[b] = __builtin_amdgcn_mfma_f32_16x16x32_bf16(a0, bf, acc0[b], 0, 0, 0);
      acc1[b] = __builtin_amdgcn_mfma_f32_16x16x32_bf16(a1, bf, acc1[b], 0, 0, 0);
    }
    __syncthreads();
  }

  // epilogue: D[m=(q*4+r)][n=16b+m16]
#pragma unroll
  for (int t = 0; t < 2; ++t) {
    int node_base = n0 + w * 32 + t * 16 + q * 4;
#pragma unroll
    for (int b = 0; b < 13; ++b) {
      int n = b * 16 + m16;
#pragma unroll
      for (int r = 0; r < 4; ++r) {
        int node = node_base + r;
        if (node >= N_NODES) continue;
        float v = t == 0 ? acc0[b][r] : acc1[b][r];
        if (n < 100) {
          Zrel[(size_t)node * 100 + n] = f2bf(v);
        } else if (n < 200) {
          Zroot[(size_t)node * 100 + (n - 100)] = f2bf(v + bias_s[n - 100]);
        }
      }
    }
  }
}

// ---------------- gather: H[i] = relu(Zroot[i] + sum Zrel[src]) in bf16, padded to 128 ----------

__global__ __launch_bounds__(256) void gather_bf16(
    const ushort_t* __restrict__ Zrel, const ushort_t* __restrict__ Zroot,
    const int* __restrict__ offs, const int* __restrict__ csr,
    ushort_t* __restrict__ H) {
  int node = blockIdx.x * 4 + (threadIdx.x >> 6);
  int lane = threadIdx.x & 63;
  int off = (lane < 50 ? lane : 49) * 2;  // ushort offset within 100-col row

  uint_t z = *(const uint_t*)(Zroot + (size_t)node * 100 + off);
  float a0 = __uint_as_float(z << 16);
  float a1 = __uint_as_float(z & 0xffff0000u);

  int s = offs[node], e = offs[node + 1];
  int j = s;
  for (; j + 1 < e; j += 2) {
    int i0 = csr[j], i1 = csr[j + 1];
    uint_t z0 = *(const uint_t*)(Zrel + (size_t)i0 * 100 + off);
    uint_t z1 = *(const uint_t*)(Zrel + (size_t)i1 * 100 + off);
    a0 += __uint_as_float(z0 << 16);
    a1 += __uint_as_float(z0 & 0xffff0000u);
    a0 += __uint_as_float(z1 << 16);
    a1 += __uint_as_float(z1 & 0xffff0000u);
  }
  if (j < e) {
    int i0 = csr[j];
    uint_t z0 = *(const uint_t*)(Zrel + (size_t)i0 * 100 + off);
    a0 += __uint_as_float(z0 << 16);
    a1 += __uint_as_float(z0 & 0xffff0000u);
  }
  a0 = fmaxf(a0, 0.f);
  a1 = fmaxf(a1, 0.f);
  uint_t outp = (uint_t)f2bf(a0) | ((uint_t)f2bf(a1) << 16);
  if (lane >= 50) outp = 0u;  // pad cols 100..127 = 0
  *(uint_t*)(H + (size_t)node * 128 + lane * 2) = outp;
}

// ---------------- global mean pool over bf16 H ----------------

__global__ void pool_kernel(const ushort_t* __restrict__ H, const int* __restrict__ batch,
                            float* __restrict__ pooled) {
  int g = blockIdx.x;
  int t = threadIdx.x;  // 128
  int lo = 0, hi = N_NODES;
  while (lo < hi) { int mid = (lo + hi) >> 1; if (batch[mid] < g) lo = mid + 1; else hi = mid; }
  int s = lo;
  hi = N_NODES;
  while (lo < hi) { int mid = (lo + hi) >> 1; if (batch[mid] <= g) lo = mid + 1; else hi = mid; }
  int e = lo;
  if (t >= F) return;
  float acc = 0.f;
  for (int n = s; n < e; ++n) {
    uint_t u = H[(size_t)n * 128 + t];
    acc += __uint_as_float(u << 16);
  }
  int cnt = e - s;
  float d = (cnt > 0) ? (float)cnt : 1.f;
  pooled[(size_t)g * F + t] = acc / d;
}

// ---------------- fused 3-layer MLP head (fp32) ----------------

__global__ void mlp_kernel(const float* __restrict__ pooled,
                           const float* __restrict__ lw1, const float* __restrict__ lb1,
                           const float* __restrict__ lw2, const float* __restrict__ lb2,
                           const float* __restrict__ lw3, const float* __restrict__ lb3,
                           float* __restrict__ out) {
  int g = blockIdx.x;
  int t = threadIdx.x;
  __shared__ float r0[F], r1[F], r2[F];
  if (t < F) r0[t] = pooled[(size_t)g * F + t];
  __syncthreads();
  if (t < F) {
    float s = lb1[t];
    for (int k = 0; k < F; ++k) s += r0[k] * lw1[t * F + k];
    r1[t] = fmaxf(s, 0.f);
  }
  __syncthreads();
  if (t < F) {
    float s = lb2[t];
    for (int k = 0; k < F; ++k) s += r1[k] * lw2[t * F + k];
    r2[t] = fmaxf(s, 0.f);
  }
  __syncthreads();
  if (t < 29) {
    float s = lb3[t];
    for (int k = 0; k < F; ++k) s += r2[k] * lw3[t * F + k];
    out[g * 29 + t] = s;
  }
}

// ---------------- launch ------------------------------------------------------------------------

extern "C" void kernel_launch(void* const* d_in, const int* in_sizes, int n_in,
                              void* d_out, int out_size, void* d_ws, size_t ws_size,
                              hipStream_t stream) {
  const float* x       = (const float*)d_in[0];
  const int*   ei      = (const int*)d_in[1];
  const int*   batch   = (const int*)d_in[2];
  const float* w1_rel  = (const float*)d_in[3];
  const float* w1_root = (const float*)d_in[4];
  const float* b1      = (const float*)d_in[5];
  const float* w_rel   = (const float*)d_in[6];
  const float* w_root  = (const float*)d_in[7];
  const float* bvec    = (const float*)d_in[8];
  const float* lw1     = (const float*)d_in[9];
  const float* lb1     = (const float*)d_in[10];
  const float* lw2     = (const float*)d_in[11];
  const float* lb2     = (const float*)d_in[12];
  const float* lw3     = (const float*)d_in[13];
  const float* lb3     = (const float*)d_in[14];
  float* out = (float*)d_out;

  // workspace layout
  char* ws = (char*)d_ws;
  size_t o = 0;
  auto alloc = [&](size_t bytes) { void* p = ws + o; o = (o + bytes + 511) & ~(size_t)511; return p; };
  ushort_t* H    = (ushort_t*)alloc((size_t)N_NODES * 128 * 2);   // 12.8 MB
  ushort_t* Zrel = (ushort_t*)alloc((size_t)N_NODES * 100 * 2);   // 10 MB
  ushort_t* Zroot= (ushort_t*)alloc((size_t)N_NODES * 100 * 2);   // 10 MB
  ushort_t* Wp1  = (ushort_t*)alloc((size_t)208 * 352 * 2);
  ushort_t* Wp   = (ushort_t*)alloc((size_t)4 * 208 * 128 * 2);
  float*    pooled = (float*)alloc((size_t)N_GRAPHS * F * 4);
  int* cnt    = (int*)alloc((size_t)(N_NODES + 1) * 4);
  int* offs   = (int*)alloc((size_t)(N_NODES + 1) * 4);
  int* cursor = (int*)alloc((size_t)(N_NODES + 1) * 4);
  int* csr    = (int*)alloc((size_t)N_EDGES * 4);

  const int E = N_EDGES;
  const int* srcv = ei;
  const int* dstv = ei + E;

  // CSR build
  hipMemsetAsync(cnt, 0, (N_NODES + 1) * sizeof(int), stream);
  hist_kernel<<<(E + 255) / 256, 256, 0, stream>>>(dstv, cnt, E);
  scan_kernel<<<1, 1024, 0, stream>>>(cnt, offs, cursor, N_NODES);
  fill_kernel<<<(E + 255) / 256, 256, 0, stream>>>(srcv, dstv, cursor, csr, E);

  // weight packing
  pack_w1_kernel<<<208, 128, 0, stream>>>(w1_rel, w1_root, Wp1);
  pack_w_kernel<<<dim3(208, 4), 128, 0, stream>>>(w_rel, w_root, Wp);

  int mmgrid = (N_NODES + 63) / 64;  // 782
  // layer 1: A = x fp32 [50000][336], Kp=352
  conv_mfma<true><<<mmgrid, 128, 0, stream>>>(x, Wp1, b1, Zrel, Zroot, 352);
  gather_bf16<<<N_NODES / 4, 256, 0, stream>>>(Zrel, Zroot, offs, csr, H);
  // layers 2..5: A = H bf16 [50000][128], Kp=128
  for (int l = 0; l < 4; ++l) {
    conv_mfma<false><<<mmgrid, 128, 0, stream>>>(H, Wp + (size_t)l * 208 * 128,
                                                 bvec + (size_t)l * F, Zrel, Zroot, 128);
    gather_bf16<<<N_NODES / 4, 256, 0, stream>>>(Zrel, Zroot, offs, csr, H);
  }
  pool_kernel<<<N_GRAPHS, 128, 0, stream>>>(H, batch, pooled);
  mlp_kernel<<<N_GRAPHS, 128, 0, stream>>>(pooled, lw1, lb1, lw2, lb2, lw3, lb3, out);
}

// Round 3
// 548.676 us; speedup vs baseline: 2.3438x; 1.3611x over previous
//
#include <hip/hip_runtime.h>

#define N_NODES 50000
#define N_EDGES 800000
#define N_GRAPHS 256
#define F 100  // hidden dim

#define SCAN_B 512
#define SCAN_NB 98          // 98*512 = 50176 >= 50001
#define SCAN_PAD (SCAN_NB * SCAN_B)

typedef __attribute__((ext_vector_type(8))) short bf16x8;
typedef __attribute__((ext_vector_type(4))) float f32x4;
typedef unsigned short ushort_t;
typedef unsigned int uint_t;

__device__ inline ushort_t f2bf(float f) {  // RNE float->bf16
  uint_t u = __float_as_uint(f);
  uint_t r = (u + 0x7fffu + ((u >> 16) & 1u)) >> 16;
  return (ushort_t)r;
}

// ---------------- CSR build (counting sort by dst, rebuilt every call) ----------------

__global__ void hist_kernel(const int* __restrict__ dst, int* __restrict__ cnt, int E) {
  int e = blockIdx.x * blockDim.x + threadIdx.x;
  if (e < E) atomicAdd(&cnt[dst[e]], 1);
}

// phase 1: per-block exclusive scan of 512 counts + block total
__global__ __launch_bounds__(SCAN_B) void scan1_kernel(const int* __restrict__ cnt,
                                                       int* __restrict__ excl,
                                                       int* __restrict__ bsum) {
  __shared__ int sh[SCAN_B];
  int t = threadIdx.x;
  int i = blockIdx.x * SCAN_B + t;
  int v = cnt[i];  // cnt is zero-initialized over full padded range
  sh[t] = v;
  __syncthreads();
  for (int off = 1; off < SCAN_B; off <<= 1) {
    int u = (t >= off) ? sh[t - off] : 0;
    __syncthreads();
    sh[t] += u;
    __syncthreads();
  }
  excl[i] = sh[t] - v;
  if (t == SCAN_B - 1) bsum[blockIdx.x] = sh[t];
}

// phase 2: exclusive scan of the 98 block totals (in place)
__global__ __launch_bounds__(128) void scan2_kernel(int* __restrict__ bsum) {
  __shared__ int sh[128];
  int t = threadIdx.x;
  int v = (t < SCAN_NB) ? bsum[t] : 0;
  sh[t] = v;
  __syncthreads();
  for (int off = 1; off < 128; off <<= 1) {
    int u = (t >= off) ? sh[t - off] : 0;
    __syncthreads();
    sh[t] += u;
    __syncthreads();
  }
  if (t < SCAN_NB) bsum[t] = sh[t] - v;
}

// phase 3: offs[i] = excl[i] + bsum[blk]; also init cursor
__global__ __launch_bounds__(SCAN_B) void scan3_kernel(const int* __restrict__ excl,
                                                       const int* __restrict__ bsum,
                                                       int* __restrict__ offs,
                                                       int* __restrict__ cursor) {
  int i = blockIdx.x * SCAN_B + threadIdx.x;
  int v = excl[i] + bsum[blockIdx.x];
  if (i <= N_NODES) { offs[i] = v; cursor[i] = v; }
}

__global__ void fill_kernel(const int* __restrict__ src, const int* __restrict__ dst,
                            int* __restrict__ cursor, int* __restrict__ csr_src, int E) {
  int e = blockIdx.x * blockDim.x + threadIdx.x;
  if (e < E) {
    int p = atomicAdd(&cursor[dst[e]], 1);
    csr_src[p] = src[e];
  }
}

// ---------------- weight packing: [208][Kp] bf16, zero-padded ----------------

__global__ void pack_w1_kernel(const float* __restrict__ w1_rel, const float* __restrict__ w1_root,
                               ushort_t* __restrict__ Wp1) {
  int row = blockIdx.x;  // 208
  for (int k = threadIdx.x; k < 352; k += 128) {
    float v = 0.f;
    if (k < 336) {
      if (row < 100) v = w1_rel[row * 336 + k];
      else if (row < 200) v = w1_root[(row - 100) * 336 + k];
    }
    Wp1[(size_t)row * 352 + k] = f2bf(v);
  }
}

__global__ void pack_w_kernel(const float* __restrict__ w_rel, const float* __restrict__ w_root,
                              ushort_t* __restrict__ Wp) {
  int row = blockIdx.x;  // 208
  int l = blockIdx.y;    // 4
  int k = threadIdx.x;   // 128
  float v = 0.f;
  if (k < 100) {
    if (row < 100) v = w_rel[((size_t)l * 100 + row) * 100 + k];
    else if (row < 200) v = w_root[((size_t)l * 100 + row - 100) * 100 + k];
  }
  Wp[((size_t)l * 208 + row) * 128 + k] = f2bf(v);
}

// ---------------- MFMA conv: Zrel = A@Wrel.T (bf16), Zroot = A@Wroot.T + b ----------------
// Block: 128 threads = 2 waves. Block tile: 64 nodes x 208 feats.
// mfma_f32_16x16x32_bf16 layouts (m89/m91-verified):
//   A: lane holds A[m=lane&15][k=(lane>>4)*8+j]; B: B[k=(lane>>4)*8+j][n=lane&15]
//   D: lane,reg -> D[m=(lane>>4)*4+reg][n=lane&15]

template <bool AF32>
__global__ __launch_bounds__(128) void conv_mfma(
    const void* __restrict__ Aptr, const ushort_t* __restrict__ Wp,
    const float* __restrict__ bias,
    ushort_t* __restrict__ Zrel, ushort_t* __restrict__ Zroot, int Kp) {
  __shared__ short alds[4 * 64 * 8];    // [q][row64][8]  4 KB
  __shared__ short blds[4 * 208 * 8];   // [q][row208][8] 13.3 KB
  __shared__ float bias_s[100];

  int tid = threadIdx.x;
  int n0 = blockIdx.x * 64;
  if (tid < 100) bias_s[tid] = bias[tid];

  f32x4 acc0[13], acc1[13];
#pragma unroll
  for (int b = 0; b < 13; ++b) { acc0[b] = (f32x4)0.f; acc1[b] = (f32x4)0.f; }

  int w = tid >> 6, lane = tid & 63, q = lane >> 4, m16 = lane & 15;

  for (int k0 = 0; k0 < Kp; k0 += 32) {
    // stage A: 64 rows x 4 quads of 8 bf16
#pragma unroll
    for (int i = tid; i < 256; i += 128) {
      int nl = i >> 2, qq = i & 3;
      int node = n0 + nl;
      bf16x8 val = (bf16x8)0;
      if (AF32) {
        int k = k0 + qq * 8;
        if (node < N_NODES && k < 336) {
          const float* p = (const float*)Aptr + (size_t)node * 336 + k;
          float4 f0 = *(const float4*)p;
          float4 f1 = *(const float4*)(p + 4);
          val[0] = (short)f2bf(f0.x); val[1] = (short)f2bf(f0.y);
          val[2] = (short)f2bf(f0.z); val[3] = (short)f2bf(f0.w);
          val[4] = (short)f2bf(f1.x); val[5] = (short)f2bf(f1.y);
          val[6] = (short)f2bf(f1.z); val[7] = (short)f2bf(f1.w);
        }
      } else {
        if (node < N_NODES)
          val = *(const bf16x8*)((const short*)Aptr + (size_t)node * 128 + k0 + qq * 8);
      }
      *(bf16x8*)&alds[(qq * 64 + nl) * 8] = val;
    }
    // stage B: 208 rows x 4 quads
    for (int i = tid; i < 832; i += 128) {
      int n = i >> 2, qq = i & 3;
      *(bf16x8*)&blds[(qq * 208 + n) * 8] =
          *(const bf16x8*)((const short*)Wp + (size_t)n * Kp + k0 + qq * 8);
    }
    __syncthreads();
    bf16x8 a0 = *(const bf16x8*)&alds[(q * 64 + w * 32 + m16) * 8];
    bf16x8 a1 = *(const bf16x8*)&alds[(q * 64 + w * 32 + 16 + m16) * 8];
#pragma unroll
    for (int b = 0; b < 13; ++b) {
      bf16x8 bf = *(const bf16x8*)&blds[(q * 208 + b * 16 + m16) * 8];
      acc0[b] = __builtin_amdgcn_mfma_f32_16x16x32_bf16(a0, bf, acc0[b], 0, 0, 0);
      acc1[b] = __builtin_amdgcn_mfma_f32_16x16x32_bf16(a1, bf, acc1[b], 0, 0, 0);
    }
    __syncthreads();
  }

  // epilogue: D[m=(q*4+r)][n=16b+m16]
#pragma unroll
  for (int t = 0; t < 2; ++t) {
    int node_base = n0 + w * 32 + t * 16 + q * 4;
#pragma unroll
    for (int b = 0; b < 13; ++b) {
      int n = b * 16 + m16;
#pragma unroll
      for (int r = 0; r < 4; ++r) {
        int node = node_base + r;
        if (node >= N_NODES) continue;
        float v = t == 0 ? acc0[b][r] : acc1[b][r];
        if (n < 100) {
          Zrel[(size_t)node * 100 + n] = f2bf(v);
        } else if (n < 200) {
          Zroot[(size_t)node * 100 + (n - 100)] = f2bf(v + bias_s[n - 100]);
        }
      }
    }
  }
}

// ---------------- gather: H[i] = relu(Zroot[i] + sum Zrel[src]) in bf16, padded to 128 ----------
// One wave per node; scalar offs/csr loads; 4-edge unroll with independent accumulators.

__global__ __launch_bounds__(256) void gather_bf16(
    const ushort_t* __restrict__ Zrel, const ushort_t* __restrict__ Zroot,
    const int* __restrict__ offs, const int* __restrict__ csr,
    ushort_t* __restrict__ H) {
  int node = blockIdx.x * 4 + (threadIdx.x >> 6);
  node = __builtin_amdgcn_readfirstlane(node);  // force wave-uniform -> scalar loads
  int lane = threadIdx.x & 63;
  int off = (lane < 50 ? lane : 49) * 2;  // ushort offset within 100-col row

  uint_t z = *(const uint_t*)(Zroot + (size_t)node * 100 + off);
  float a0 = __uint_as_float(z << 16);
  float a1 = __uint_as_float(z & 0xffff0000u);
  float b0 = 0.f, b1 = 0.f, c0 = 0.f, c1 = 0.f, d0 = 0.f, d1 = 0.f;

  int s = offs[node], e = offs[node + 1];
  int j = s;
  for (; j + 3 < e; j += 4) {
    int i0 = csr[j], i1 = csr[j + 1], i2 = csr[j + 2], i3 = csr[j + 3];
    uint_t z0 = *(const uint_t*)(Zrel + (size_t)i0 * 100 + off);
    uint_t z1 = *(const uint_t*)(Zrel + (size_t)i1 * 100 + off);
    uint_t z2 = *(const uint_t*)(Zrel + (size_t)i2 * 100 + off);
    uint_t z3 = *(const uint_t*)(Zrel + (size_t)i3 * 100 + off);
    a0 += __uint_as_float(z0 << 16); a1 += __uint_as_float(z0 & 0xffff0000u);
    b0 += __uint_as_float(z1 << 16); b1 += __uint_as_float(z1 & 0xffff0000u);
    c0 += __uint_as_float(z2 << 16); c1 += __uint_as_float(z2 & 0xffff0000u);
    d0 += __uint_as_float(z3 << 16); d1 += __uint_as_float(z3 & 0xffff0000u);
  }
  for (; j < e; ++j) {
    int i0 = csr[j];
    uint_t z0 = *(const uint_t*)(Zrel + (size_t)i0 * 100 + off);
    a0 += __uint_as_float(z0 << 16);
    a1 += __uint_as_float(z0 & 0xffff0000u);
  }
  a0 = fmaxf(a0 + b0 + c0 + d0, 0.f);
  a1 = fmaxf(a1 + b1 + c1 + d1, 0.f);
  uint_t outp = (uint_t)f2bf(a0) | ((uint_t)f2bf(a1) << 16);
  if (lane >= 50) outp = 0u;  // pad cols 100..127 = 0
  *(uint_t*)(H + (size_t)node * 128 + lane * 2) = outp;
}

// ---------------- global mean pool over bf16 H ----------------

__global__ void pool_kernel(const ushort_t* __restrict__ H, const int* __restrict__ batch,
                            float* __restrict__ pooled) {
  int g = blockIdx.x;
  int t = threadIdx.x;  // 128
  int lo = 0, hi = N_NODES;
  while (lo < hi) { int mid = (lo + hi) >> 1; if (batch[mid] < g) lo = mid + 1; else hi = mid; }
  int s = lo;
  hi = N_NODES;
  while (lo < hi) { int mid = (lo + hi) >> 1; if (batch[mid] <= g) lo = mid + 1; else hi = mid; }
  int e = lo;
  if (t >= F) return;
  float acc = 0.f;
  for (int n = s; n < e; ++n) {
    uint_t u = H[(size_t)n * 128 + t];
    acc += __uint_as_float(u << 16);
  }
  int cnt = e - s;
  float d = (cnt > 0) ? (float)cnt : 1.f;
  pooled[(size_t)g * F + t] = acc / d;
}

// ---------------- fused 3-layer MLP head (fp32) ----------------

__global__ void mlp_kernel(const float* __restrict__ pooled,
                           const float* __restrict__ lw1, const float* __restrict__ lb1,
                           const float* __restrict__ lw2, const float* __restrict__ lb2,
                           const float* __restrict__ lw3, const float* __restrict__ lb3,
                           float* __restrict__ out) {
  int g = blockIdx.x;
  int t = threadIdx.x;
  __shared__ float r0[F], r1[F], r2[F];
  if (t < F) r0[t] = pooled[(size_t)g * F + t];
  __syncthreads();
  if (t < F) {
    float s = lb1[t];
    for (int k = 0; k < F; ++k) s += r0[k] * lw1[t * F + k];
    r1[t] = fmaxf(s, 0.f);
  }
  __syncthreads();
  if (t < F) {
    float s = lb2[t];
    for (int k = 0; k < F; ++k) s += r1[k] * lw2[t * F + k];
    r2[t] = fmaxf(s, 0.f);
  }
  __syncthreads();
  if (t < 29) {
    float s = lb3[t];
    for (int k = 0; k < F; ++k) s += r2[k] * lw3[t * F + k];
    out[g * 29 + t] = s;
  }
}

// ---------------- launch ------------------------------------------------------------------------

extern "C" void kernel_launch(void* const* d_in, const int* in_sizes, int n_in,
                              void* d_out, int out_size, void* d_ws, size_t ws_size,
                              hipStream_t stream) {
  const float* x       = (const float*)d_in[0];
  const int*   ei      = (const int*)d_in[1];
  const int*   batch   = (const int*)d_in[2];
  const float* w1_rel  = (const float*)d_in[3];
  const float* w1_root = (const float*)d_in[4];
  const float* b1      = (const float*)d_in[5];
  const float* w_rel   = (const float*)d_in[6];
  const float* w_root  = (const float*)d_in[7];
  const float* bvec    = (const float*)d_in[8];
  const float* lw1     = (const float*)d_in[9];
  const float* lb1     = (const float*)d_in[10];
  const float* lw2     = (const float*)d_in[11];
  const float* lb2     = (const float*)d_in[12];
  const float* lw3     = (const float*)d_in[13];
  const float* lb3     = (const float*)d_in[14];
  float* out = (float*)d_out;

  // workspace layout
  char* ws = (char*)d_ws;
  size_t o = 0;
  auto alloc = [&](size_t bytes) { void* p = ws + o; o = (o + bytes + 511) & ~(size_t)511; return p; };
  ushort_t* H    = (ushort_t*)alloc((size_t)N_NODES * 128 * 2);   // 12.8 MB
  ushort_t* Zrel = (ushort_t*)alloc((size_t)N_NODES * 100 * 2);   // 10 MB
  ushort_t* Zroot= (ushort_t*)alloc((size_t)N_NODES * 100 * 2);   // 10 MB
  ushort_t* Wp1  = (ushort_t*)alloc((size_t)208 * 352 * 2);
  ushort_t* Wp   = (ushort_t*)alloc((size_t)4 * 208 * 128 * 2);
  float*    pooled = (float*)alloc((size_t)N_GRAPHS * F * 4);
  int* cnt    = (int*)alloc((size_t)SCAN_PAD * 4);
  int* excl   = (int*)alloc((size_t)SCAN_PAD * 4);
  int* bsum   = (int*)alloc((size_t)128 * 4);
  int* offs   = (int*)alloc((size_t)(N_NODES + 1) * 4);
  int* cursor = (int*)alloc((size_t)(N_NODES + 1) * 4);
  int* csr    = (int*)alloc((size_t)N_EDGES * 4);

  const int E = N_EDGES;
  const int* srcv = ei;
  const int* dstv = ei + E;

  // CSR build (parallel 3-phase scan)
  hipMemsetAsync(cnt, 0, (size_t)SCAN_PAD * sizeof(int), stream);
  hist_kernel<<<(E + 255) / 256, 256, 0, stream>>>(dstv, cnt, E);
  scan1_kernel<<<SCAN_NB, SCAN_B, 0, stream>>>(cnt, excl, bsum);
  scan2_kernel<<<1, 128, 0, stream>>>(bsum);
  scan3_kernel<<<SCAN_NB, SCAN_B, 0, stream>>>(excl, bsum, offs, cursor);
  fill_kernel<<<(E + 255) / 256, 256, 0, stream>>>(srcv, dstv, cursor, csr, E);

  // weight packing
  pack_w1_kernel<<<208, 128, 0, stream>>>(w1_rel, w1_root, Wp1);
  pack_w_kernel<<<dim3(208, 4), 128, 0, stream>>>(w_rel, w_root, Wp);

  int mmgrid = (N_NODES + 63) / 64;  // 782
  // layer 1: A = x fp32 [50000][336], Kp=352
  conv_mfma<true><<<mmgrid, 128, 0, stream>>>(x, Wp1, b1, Zrel, Zroot, 352);
  gather_bf16<<<N_NODES / 4, 256, 0, stream>>>(Zrel, Zroot, offs, csr, H);
  // layers 2..5: A = H bf16 [50000][128], Kp=128
  for (int l = 0; l < 4; ++l) {
    conv_mfma<false><<<mmgrid, 128, 0, stream>>>(H, Wp + (size_t)l * 208 * 128,
                                                 bvec + (size_t)l * F, Zrel, Zroot, 128);
    gather_bf16<<<N_NODES / 4, 256, 0, stream>>>(Zrel, Zroot, offs, csr, H);
  }
  pool_kernel<<<N_GRAPHS, 128, 0, stream>>>(H, batch, pooled);
  mlp_kernel<<<N_GRAPHS, 128, 0, stream>>>(pooled, lw1, lb1, lw2, lb2, lw3, lb3, out);
}

// Round 4
// 501.922 us; speedup vs baseline: 2.5621x; 1.0931x over previous
//
#include <hip/hip_runtime.h>

#define N_NODES 50000
#define N_EDGES 800000
#define N_GRAPHS 256
#define F 100  // hidden dim

#define SCAN_B 512
#define SCAN_NB 98          // 98*512 = 50176 >= 50001
#define SCAN_PAD (SCAN_NB * SCAN_B)

typedef __attribute__((ext_vector_type(8))) short bf16x8;
typedef __attribute__((ext_vector_type(4))) float f32x4;
typedef unsigned short ushort_t;
typedef unsigned int uint_t;

__device__ inline ushort_t f2bf(float f) {  // RNE float->bf16
  uint_t u = __float_as_uint(f);
  uint_t r = (u + 0x7fffu + ((u >> 16) & 1u)) >> 16;
  return (ushort_t)r;
}

// ---------------- CSR build (counting sort by dst, rebuilt every call) ----------------

__global__ void hist_kernel(const int* __restrict__ dst, int* __restrict__ cnt, int E) {
  int e = blockIdx.x * blockDim.x + threadIdx.x;
  if (e < E) atomicAdd(&cnt[dst[e]], 1);
}

// phase 1: per-block exclusive scan of 512 counts + block total
__global__ __launch_bounds__(SCAN_B) void scan1_kernel(const int* __restrict__ cnt,
                                                       int* __restrict__ excl,
                                                       int* __restrict__ bsum) {
  __shared__ int sh[SCAN_B];
  int t = threadIdx.x;
  int i = blockIdx.x * SCAN_B + t;
  int v = cnt[i];  // cnt is zero-initialized over full padded range
  sh[t] = v;
  __syncthreads();
  for (int off = 1; off < SCAN_B; off <<= 1) {
    int u = (t >= off) ? sh[t - off] : 0;
    __syncthreads();
    sh[t] += u;
    __syncthreads();
  }
  excl[i] = sh[t] - v;
  if (t == SCAN_B - 1) bsum[blockIdx.x] = sh[t];
}

// phase 2: exclusive scan of the 98 block totals (in place)
__global__ __launch_bounds__(128) void scan2_kernel(int* __restrict__ bsum) {
  __shared__ int sh[128];
  int t = threadIdx.x;
  int v = (t < SCAN_NB) ? bsum[t] : 0;
  sh[t] = v;
  __syncthreads();
  for (int off = 1; off < 128; off <<= 1) {
    int u = (t >= off) ? sh[t - off] : 0;
    __syncthreads();
    sh[t] += u;
    __syncthreads();
  }
  if (t < SCAN_NB) bsum[t] = sh[t] - v;
}

// phase 3: offs[i] = excl[i] + bsum[blk]; also init cursor
__global__ __launch_bounds__(SCAN_B) void scan3_kernel(const int* __restrict__ excl,
                                                       const int* __restrict__ bsum,
                                                       int* __restrict__ offs,
                                                       int* __restrict__ cursor) {
  int i = blockIdx.x * SCAN_B + threadIdx.x;
  int v = excl[i] + bsum[blockIdx.x];
  if (i <= N_NODES) { offs[i] = v; cursor[i] = v; }
}

__global__ void fill_kernel(const int* __restrict__ src, const int* __restrict__ dst,
                            int* __restrict__ cursor, int* __restrict__ csr_src, int E) {
  int e = blockIdx.x * blockDim.x + threadIdx.x;
  if (e < E) {
    int p = atomicAdd(&cursor[dst[e]], 1);
    csr_src[p] = src[e];
  }
}

// ---------------- weight packing: [208][Kp] bf16, zero-padded ----------------

__global__ void pack_w1_kernel(const float* __restrict__ w1_rel, const float* __restrict__ w1_root,
                               ushort_t* __restrict__ Wp1) {
  int row = blockIdx.x;  // 208
  for (int k = threadIdx.x; k < 352; k += 128) {
    float v = 0.f;
    if (k < 336) {
      if (row < 100) v = w1_rel[row * 336 + k];
      else if (row < 200) v = w1_root[(row - 100) * 336 + k];
    }
    Wp1[(size_t)row * 352 + k] = f2bf(v);
  }
}

__global__ void pack_w_kernel(const float* __restrict__ w_rel, const float* __restrict__ w_root,
                              ushort_t* __restrict__ Wp) {
  int row = blockIdx.x;  // 208
  int l = blockIdx.y;    // 4
  int k = threadIdx.x;   // 128
  float v = 0.f;
  if (k < 100) {
    if (row < 100) v = w_rel[((size_t)l * 100 + row) * 100 + k];
    else if (row < 200) v = w_root[((size_t)l * 100 + row - 100) * 100 + k];
  }
  Wp[((size_t)l * 208 + row) * 128 + k] = f2bf(v);
}

// ---------------- MFMA conv: Zrel = A@Wrel.T (bf16), Zroot = A@Wroot.T + b ----------------
// Block: 128 threads = 2 waves. Block tile: 64 nodes x 208 feats.
// mfma_f32_16x16x32_bf16 layouts (m89/m91-verified):
//   A: lane holds A[m=lane&15][k=(lane>>4)*8+j]; B: B[k=(lane>>4)*8+j][n=lane&15]
//   D: lane,reg -> D[m=(lane>>4)*4+reg][n=lane&15]

template <bool AF32>
__global__ __launch_bounds__(128) void conv_mfma(
    const void* __restrict__ Aptr, const ushort_t* __restrict__ Wp,
    const float* __restrict__ bias,
    ushort_t* __restrict__ Zrel, ushort_t* __restrict__ Zroot, int Kp) {
  __shared__ short alds[4 * 64 * 8];    // [q][row64][8]  4 KB
  __shared__ short blds[4 * 208 * 8];   // [q][row208][8] 13.3 KB
  __shared__ float bias_s[100];

  int tid = threadIdx.x;
  int n0 = blockIdx.x * 64;
  if (tid < 100) bias_s[tid] = bias[tid];

  f32x4 acc0[13], acc1[13];
#pragma unroll
  for (int b = 0; b < 13; ++b) { acc0[b] = (f32x4)0.f; acc1[b] = (f32x4)0.f; }

  int w = tid >> 6, lane = tid & 63, q = lane >> 4, m16 = lane & 15;

  for (int k0 = 0; k0 < Kp; k0 += 32) {
    // stage A: 64 rows x 4 quads of 8 bf16
#pragma unroll
    for (int i = tid; i < 256; i += 128) {
      int nl = i >> 2, qq = i & 3;
      int node = n0 + nl;
      bf16x8 val = (bf16x8)0;
      if (AF32) {
        int k = k0 + qq * 8;
        if (node < N_NODES && k < 336) {
          const float* p = (const float*)Aptr + (size_t)node * 336 + k;
          float4 f0 = *(const float4*)p;
          float4 f1 = *(const float4*)(p + 4);
          val[0] = (short)f2bf(f0.x); val[1] = (short)f2bf(f0.y);
          val[2] = (short)f2bf(f0.z); val[3] = (short)f2bf(f0.w);
          val[4] = (short)f2bf(f1.x); val[5] = (short)f2bf(f1.y);
          val[6] = (short)f2bf(f1.z); val[7] = (short)f2bf(f1.w);
        }
      } else {
        if (node < N_NODES)
          val = *(const bf16x8*)((const short*)Aptr + (size_t)node * 128 + k0 + qq * 8);
      }
      *(bf16x8*)&alds[(qq * 64 + nl) * 8] = val;
    }
    // stage B: 208 rows x 4 quads
    for (int i = tid; i < 832; i += 128) {
      int n = i >> 2, qq = i & 3;
      *(bf16x8*)&blds[(qq * 208 + n) * 8] =
          *(const bf16x8*)((const short*)Wp + (size_t)n * Kp + k0 + qq * 8);
    }
    __syncthreads();
    bf16x8 a0 = *(const bf16x8*)&alds[(q * 64 + w * 32 + m16) * 8];
    bf16x8 a1 = *(const bf16x8*)&alds[(q * 64 + w * 32 + 16 + m16) * 8];
#pragma unroll
    for (int b = 0; b < 13; ++b) {
      bf16x8 bf = *(const bf16x8*)&blds[(q * 208 + b * 16 + m16) * 8];
      acc0[b] = __builtin_amdgcn_mfma_f32_16x16x32_bf16(a0, bf, acc0[b], 0, 0, 0);
      acc1[b] = __builtin_amdgcn_mfma_f32_16x16x32_bf16(a1, bf, acc1[b], 0, 0, 0);
    }
    __syncthreads();
  }

  // epilogue: D[m=(q*4+r)][n=16b+m16]
#pragma unroll
  for (int t = 0; t < 2; ++t) {
    int node_base = n0 + w * 32 + t * 16 + q * 4;
#pragma unroll
    for (int b = 0; b < 13; ++b) {
      int n = b * 16 + m16;
#pragma unroll
      for (int r = 0; r < 4; ++r) {
        int node = node_base + r;
        if (node >= N_NODES) continue;
        float v = t == 0 ? acc0[b][r] : acc1[b][r];
        if (n < 100) {
          Zrel[(size_t)node * 100 + n] = f2bf(v);
        } else if (n < 200) {
          Zroot[(size_t)node * 100 + (n - 100)] = f2bf(v + bias_s[n - 100]);
        }
      }
    }
  }
}

// ---------------- gather: H[i] = relu(Zroot[i] + sum Zrel[src]) in bf16, padded to 128 ----------
// One wave per node; scalar offs/csr loads; 8-edge unroll with independent accumulators.

__global__ __launch_bounds__(256) void gather_bf16(
    const ushort_t* __restrict__ Zrel, const ushort_t* __restrict__ Zroot,
    const int* __restrict__ offs, const int* __restrict__ csr,
    ushort_t* __restrict__ H) {
  int node = blockIdx.x * 4 + (threadIdx.x >> 6);
  node = __builtin_amdgcn_readfirstlane(node);  // force wave-uniform -> scalar loads
  int lane = threadIdx.x & 63;
  int off = (lane < 50 ? lane : 49) * 2;  // ushort offset within 100-col row

  uint_t z = *(const uint_t*)(Zroot + (size_t)node * 100 + off);
  float p0[8], p1[8];
#pragma unroll
  for (int u = 0; u < 8; ++u) { p0[u] = 0.f; p1[u] = 0.f; }
  p0[0] = __uint_as_float(z << 16);
  p1[0] = __uint_as_float(z & 0xffff0000u);

  int s = offs[node], e = offs[node + 1];
  int j = s;
  for (; j + 7 < e; j += 8) {
    uint_t zz[8];
#pragma unroll
    for (int u = 0; u < 8; ++u) {
      int idx = csr[j + u];
      zz[u] = *(const uint_t*)(Zrel + (size_t)idx * 100 + off);
    }
#pragma unroll
    for (int u = 0; u < 8; ++u) {
      p0[u] += __uint_as_float(zz[u] << 16);
      p1[u] += __uint_as_float(zz[u] & 0xffff0000u);
    }
  }
  for (; j < e; ++j) {
    int idx = csr[j];
    uint_t z0 = *(const uint_t*)(Zrel + (size_t)idx * 100 + off);
    p0[0] += __uint_as_float(z0 << 16);
    p1[0] += __uint_as_float(z0 & 0xffff0000u);
  }
  float a0 = ((p0[0] + p0[1]) + (p0[2] + p0[3])) + ((p0[4] + p0[5]) + (p0[6] + p0[7]));
  float a1 = ((p1[0] + p1[1]) + (p1[2] + p1[3])) + ((p1[4] + p1[5]) + (p1[6] + p1[7]));
  a0 = fmaxf(a0, 0.f);
  a1 = fmaxf(a1, 0.f);
  uint_t outp = (uint_t)f2bf(a0) | ((uint_t)f2bf(a1) << 16);
  if (lane >= 50) outp = 0u;  // pad cols 100..127 = 0
  *(uint_t*)(H + (size_t)node * 128 + lane * 2) = outp;
}

// ---------------- global mean pool: 1 block/graph, 16 node-rows x 64 lanes ----------------

__global__ __launch_bounds__(1024) void pool_kernel(const ushort_t* __restrict__ H,
                                                    const int* __restrict__ batch,
                                                    float* __restrict__ pooled) {
  int g = blockIdx.x;
  int t = threadIdx.x;
  int lo = 0, hi = N_NODES;
  while (lo < hi) { int mid = (lo + hi) >> 1; if (batch[mid] < g) lo = mid + 1; else hi = mid; }
  int s = lo;
  hi = N_NODES;
  while (lo < hi) { int mid = (lo + hi) >> 1; if (batch[mid] <= g) lo = mid + 1; else hi = mid; }
  int e = lo;

  int row = t >> 6;      // 16 node-rows
  int lane = t & 63;
  int off = (lane < 50 ? lane : 49) * 2;
  float a0 = 0.f, a1 = 0.f;
  for (int n = s + row; n < e; n += 16) {
    uint_t z = *(const uint_t*)(H + (size_t)n * 128 + off);
    a0 += __uint_as_float(z << 16);
    a1 += __uint_as_float(z & 0xffff0000u);
  }
  __shared__ float sh[16][104];
  if (lane < 50) { sh[row][lane * 2] = a0; sh[row][lane * 2 + 1] = a1; }
  __syncthreads();
  if (t < 100) {
    float acc = 0.f;
#pragma unroll
    for (int r = 0; r < 16; ++r) acc += sh[r][t];
    int cnt = e - s;
    float d = (cnt > 0) ? (float)cnt : 1.f;
    pooled[(size_t)g * F + t] = acc / d;
  }
}

// ---------------- fused 3-layer MLP head (fp32) ----------------

__global__ void mlp_kernel(const float* __restrict__ pooled,
                           const float* __restrict__ lw1, const float* __restrict__ lb1,
                           const float* __restrict__ lw2, const float* __restrict__ lb2,
                           const float* __restrict__ lw3, const float* __restrict__ lb3,
                           float* __restrict__ out) {
  int g = blockIdx.x;
  int t = threadIdx.x;
  __shared__ float r0[F], r1[F], r2[F];
  if (t < F) r0[t] = pooled[(size_t)g * F + t];
  __syncthreads();
  if (t < F) {
    float s = lb1[t];
    for (int k = 0; k < F; ++k) s += r0[k] * lw1[t * F + k];
    r1[t] = fmaxf(s, 0.f);
  }
  __syncthreads();
  if (t < F) {
    float s = lb2[t];
    for (int k = 0; k < F; ++k) s += r1[k] * lw2[t * F + k];
    r2[t] = fmaxf(s, 0.f);
  }
  __syncthreads();
  if (t < 29) {
    float s = lb3[t];
    for (int k = 0; k < F; ++k) s += r2[k] * lw3[t * F + k];
    out[g * 29 + t] = s;
  }
}

// ---------------- launch ------------------------------------------------------------------------

extern "C" void kernel_launch(void* const* d_in, const int* in_sizes, int n_in,
                              void* d_out, int out_size, void* d_ws, size_t ws_size,
                              hipStream_t stream) {
  const float* x       = (const float*)d_in[0];
  const int*   ei      = (const int*)d_in[1];
  const int*   batch   = (const int*)d_in[2];
  const float* w1_rel  = (const float*)d_in[3];
  const float* w1_root = (const float*)d_in[4];
  const float* b1      = (const float*)d_in[5];
  const float* w_rel   = (const float*)d_in[6];
  const float* w_root  = (const float*)d_in[7];
  const float* bvec    = (const float*)d_in[8];
  const float* lw1     = (const float*)d_in[9];
  const float* lb1     = (const float*)d_in[10];
  const float* lw2     = (const float*)d_in[11];
  const float* lb2     = (const float*)d_in[12];
  const float* lw3     = (const float*)d_in[13];
  const float* lb3     = (const float*)d_in[14];
  float* out = (float*)d_out;

  // workspace layout
  char* ws = (char*)d_ws;
  size_t o = 0;
  auto alloc = [&](size_t bytes) { void* p = ws + o; o = (o + bytes + 511) & ~(size_t)511; return p; };
  ushort_t* H    = (ushort_t*)alloc((size_t)N_NODES * 128 * 2);   // 12.8 MB
  ushort_t* Zrel = (ushort_t*)alloc((size_t)N_NODES * 100 * 2);   // 10 MB
  ushort_t* Zroot= (ushort_t*)alloc((size_t)N_NODES * 100 * 2);   // 10 MB
  ushort_t* Wp1  = (ushort_t*)alloc((size_t)208 * 352 * 2);
  ushort_t* Wp   = (ushort_t*)alloc((size_t)4 * 208 * 128 * 2);
  float*    pooled = (float*)alloc((size_t)N_GRAPHS * F * 4);
  int* cnt    = (int*)alloc((size_t)SCAN_PAD * 4);
  int* excl   = (int*)alloc((size_t)SCAN_PAD * 4);
  int* bsum   = (int*)alloc((size_t)128 * 4);
  int* offs   = (int*)alloc((size_t)(N_NODES + 1) * 4);
  int* cursor = (int*)alloc((size_t)(N_NODES + 1) * 4);
  int* csr    = (int*)alloc((size_t)N_EDGES * 4);

  const int E = N_EDGES;
  const int* srcv = ei;
  const int* dstv = ei + E;

  // CSR build (parallel 3-phase scan)
  hipMemsetAsync(cnt, 0, (size_t)SCAN_PAD * sizeof(int), stream);
  hist_kernel<<<(E + 255) / 256, 256, 0, stream>>>(dstv, cnt, E);
  scan1_kernel<<<SCAN_NB, SCAN_B, 0, stream>>>(cnt, excl, bsum);
  scan2_kernel<<<1, 128, 0, stream>>>(bsum);
  scan3_kernel<<<SCAN_NB, SCAN_B, 0, stream>>>(excl, bsum, offs, cursor);
  fill_kernel<<<(E + 255) / 256, 256, 0, stream>>>(srcv, dstv, cursor, csr, E);

  // weight packing
  pack_w1_kernel<<<208, 128, 0, stream>>>(w1_rel, w1_root, Wp1);
  pack_w_kernel<<<dim3(208, 4), 128, 0, stream>>>(w_rel, w_root, Wp);

  int mmgrid = (N_NODES + 63) / 64;  // 782
  // layer 1: A = x fp32 [50000][336], Kp=352
  conv_mfma<true><<<mmgrid, 128, 0, stream>>>(x, Wp1, b1, Zrel, Zroot, 352);
  gather_bf16<<<N_NODES / 4, 256, 0, stream>>>(Zrel, Zroot, offs, csr, H);
  // layers 2..5: A = H bf16 [50000][128], Kp=128
  for (int l = 0; l < 4; ++l) {
    conv_mfma<false><<<mmgrid, 128, 0, stream>>>(H, Wp + (size_t)l * 208 * 128,
                                                 bvec + (size_t)l * F, Zrel, Zroot, 128);
    gather_bf16<<<N_NODES / 4, 256, 0, stream>>>(Zrel, Zroot, offs, csr, H);
  }
  pool_kernel<<<N_GRAPHS, 1024, 0, stream>>>(H, batch, pooled);
  mlp_kernel<<<N_GRAPHS, 128, 0, stream>>>(pooled, lw1, lb1, lw2, lb2, lw3, lb3, out);
}

// Round 6
// 475.720 us; speedup vs baseline: 2.7032x; 1.0551x over previous
//
#include <hip/hip_runtime.h>

#define N_NODES 50000
#define N_EDGES 800000
#define N_GRAPHS 256
#define F 100  // hidden dim

#define SCAN_B 512
#define SCAN_NB 98          // 98*512 = 50176 >= 50001
#define SCAN_PAD (SCAN_NB * SCAN_B)

#define PART_SZ 6250        // 8 dst partitions * 6250 = 50000
#define FILL_CHUNK 2048

typedef __attribute__((ext_vector_type(8))) short bf16x8;
typedef __attribute__((ext_vector_type(4))) float f32x4;
typedef unsigned short ushort_t;
typedef unsigned int uint_t;

__device__ inline ushort_t f2bf(float f) {  // RNE float->bf16
  uint_t u = __float_as_uint(f);
  uint_t r = (u + 0x7fffu + ((u >> 16) & 1u)) >> 16;
  return (ushort_t)r;
}

// ---------------- CSR build (counting sort by dst, rebuilt every call) ----------------
// hist/fill are dst-range partitioned with partition = blockIdx&7 so that (under the
// round-robin blockIdx->XCD heuristic) all atomic/scatter traffic for a given dst range
// stays in one XCD's L2 -> avoids 16x cross-XCD write-back amplification (R4: 52 MB
// WRITE_SIZE for a 3.2 MB csr). Correctness does not depend on the mapping.

__global__ __launch_bounds__(256) void hist_kernel(const int* __restrict__ dst,
                                                   int* __restrict__ cnt, int E) {
  int part = blockIdx.x & 7;
  int lo = part * PART_SZ, hi = lo + PART_SZ;
  int base = (blockIdx.x >> 3) * FILL_CHUNK;
  int end = base + FILL_CHUNK; if (end > E) end = E;
  for (int i = base + threadIdx.x; i < end; i += 256) {
    int d = dst[i];
    if (d >= lo && d < hi) atomicAdd(&cnt[d], 1);
  }
}

// phase 1: per-block exclusive scan of 512 counts + block total
__global__ __launch_bounds__(SCAN_B) void scan1_kernel(const int* __restrict__ cnt,
                                                       int* __restrict__ excl,
                                                       int* __restrict__ bsum) {
  __shared__ int sh[SCAN_B];
  int t = threadIdx.x;
  int i = blockIdx.x * SCAN_B + t;
  int v = cnt[i];  // cnt is zero-initialized over full padded range
  sh[t] = v;
  __syncthreads();
  for (int off = 1; off < SCAN_B; off <<= 1) {
    int u = (t >= off) ? sh[t - off] : 0;
    __syncthreads();
    sh[t] += u;
    __syncthreads();
  }
  excl[i] = sh[t] - v;
  if (t == SCAN_B - 1) bsum[blockIdx.x] = sh[t];
}

// phase 2: exclusive scan of the 98 block totals (in place)
__global__ __launch_bounds__(128) void scan2_kernel(int* __restrict__ bsum) {
  __shared__ int sh[128];
  int t = threadIdx.x;
  int v = (t < SCAN_NB) ? bsum[t] : 0;
  sh[t] = v;
  __syncthreads();
  for (int off = 1; off < 128; off <<= 1) {
    int u = (t >= off) ? sh[t - off] : 0;
    __syncthreads();
    sh[t] += u;
    __syncthreads();
  }
  if (t < SCAN_NB) bsum[t] = sh[t] - v;
}

// phase 3: offs[i] = excl[i] + bsum[blk]; also init cursor
__global__ __launch_bounds__(SCAN_B) void scan3_kernel(const int* __restrict__ excl,
                                                       const int* __restrict__ bsum,
                                                       int* __restrict__ offs,
                                                       int* __restrict__ cursor) {
  int i = blockIdx.x * SCAN_B + threadIdx.x;
  int v = excl[i] + bsum[blockIdx.x];
  if (i <= N_NODES) { offs[i] = v; cursor[i] = v; }
}

__global__ __launch_bounds__(256) void fill_kernel(const int* __restrict__ src,
                                                   const int* __restrict__ dst,
                                                   int* __restrict__ cursor,
                                                   int* __restrict__ csr_src, int E) {
  int part = blockIdx.x & 7;
  int lo = part * PART_SZ, hi = lo + PART_SZ;
  int base = (blockIdx.x >> 3) * FILL_CHUNK;
  int end = base + FILL_CHUNK; if (end > E) end = E;
  for (int i = base + threadIdx.x; i < end; i += 256) {
    int d = dst[i];
    if (d >= lo && d < hi) {
      int p = atomicAdd(&cursor[d], 1);
      csr_src[p] = src[i];
    }
  }
}

// ---------------- weight packing: [208][Kp] bf16, zero-padded ----------------

__global__ void pack_w1_kernel(const float* __restrict__ w1_rel, const float* __restrict__ w1_root,
                               ushort_t* __restrict__ Wp1) {
  int row = blockIdx.x;  // 208
  for (int k = threadIdx.x; k < 352; k += 128) {
    float v = 0.f;
    if (k < 336) {
      if (row < 100) v = w1_rel[row * 336 + k];
      else if (row < 200) v = w1_root[(row - 100) * 336 + k];
    }
    Wp1[(size_t)row * 352 + k] = f2bf(v);
  }
}

__global__ void pack_w_kernel(const float* __restrict__ w_rel, const float* __restrict__ w_root,
                              ushort_t* __restrict__ Wp) {
  int row = blockIdx.x;  // 208
  int l = blockIdx.y;    // 4
  int k = threadIdx.x;   // 128
  float v = 0.f;
  if (k < 100) {
    if (row < 100) v = w_rel[((size_t)l * 100 + row) * 100 + k];
    else if (row < 200) v = w_root[((size_t)l * 100 + row - 100) * 100 + k];
  }
  Wp[((size_t)l * 208 + row) * 128 + k] = f2bf(v);
}

// ---------------- MFMA conv: Zrel = A@Wrel.T (bf16), Zroot = A@Wroot.T + b ----------------
// Block: 256 threads = 4 waves (R5: was 2 waves; Occupancy 15% -> more waves/CU for
// latency hiding). Block tile: 64 nodes x 208 feats; wave w owns m-rows [16w,16w+16).
// mfma_f32_16x16x32_bf16 layouts (m89/m91-verified):
//   A: lane holds A[m=lane&15][k=(lane>>4)*8+j]; B: B[k=(lane>>4)*8+j][n=lane&15]
//   D: lane,reg -> D[m=(lane>>4)*4+reg][n=lane&15]

template <bool AF32>
__global__ __launch_bounds__(256) void conv_mfma(
    const void* __restrict__ Aptr, const ushort_t* __restrict__ Wp,
    const float* __restrict__ bias,
    ushort_t* __restrict__ Zrel, ushort_t* __restrict__ Zroot, int Kp) {
  __shared__ short alds[64 * 32];    // [row64][32]  4 KB, row-major
  __shared__ short blds[208 * 32];   // [row208][32] 13.3 KB
  __shared__ float bias_s[104];

  int tid = threadIdx.x;
  int n0 = blockIdx.x * 64;
  if (tid < 100) bias_s[tid] = bias[tid];

  f32x4 acc[13];
#pragma unroll
  for (int b = 0; b < 13; ++b) acc[b] = (f32x4)0.f;

  int w = tid >> 6, lane = tid & 63, q = lane >> 4, m16 = lane & 15;

  for (int k0 = 0; k0 < Kp; k0 += 32) {
    // stage A: 256 chunks of 16B, one per thread
    {
      int r = tid >> 2, qq = tid & 3;
      int node = n0 + r;
      int k = k0 + qq * 8;
      bf16x8 val = (bf16x8)0;
      if (AF32) {
        if (node < N_NODES && k < 336) {
          const float* p = (const float*)Aptr + (size_t)node * 336 + k;
          float4 f0 = *(const float4*)p;
          float4 f1 = *(const float4*)(p + 4);
          val[0] = (short)f2bf(f0.x); val[1] = (short)f2bf(f0.y);
          val[2] = (short)f2bf(f0.z); val[3] = (short)f2bf(f0.w);
          val[4] = (short)f2bf(f1.x); val[5] = (short)f2bf(f1.y);
          val[6] = (short)f2bf(f1.z); val[7] = (short)f2bf(f1.w);
        }
      } else {
        if (node < N_NODES)
          val = *(const bf16x8*)((const short*)Aptr + (size_t)node * 128 + k);
      }
      *(bf16x8*)&alds[r * 32 + qq * 8] = val;
    }
    // stage B: 832 chunks of 16B
    for (int c = tid; c < 832; c += 256) {
      int r = c >> 2, qq = c & 3;
      *(bf16x8*)&blds[r * 32 + qq * 8] =
          *(const bf16x8*)((const short*)Wp + (size_t)r * Kp + k0 + qq * 8);
    }
    __syncthreads();
    bf16x8 a = *(const bf16x8*)&alds[(w * 16 + m16) * 32 + q * 8];
#pragma unroll
    for (int b = 0; b < 13; ++b) {
      bf16x8 bf = *(const bf16x8*)&blds[(b * 16 + m16) * 32 + q * 8];
      acc[b] = __builtin_amdgcn_mfma_f32_16x16x32_bf16(a, bf, acc[b], 0, 0, 0);
    }
    __syncthreads();
  }

  // epilogue: node = n0 + w*16 + q*4 + r ; n = b*16 + m16
  int node_base = n0 + w * 16 + q * 4;
#pragma unroll
  for (int b = 0; b < 13; ++b) {
    int n = b * 16 + m16;
#pragma unroll
    for (int r = 0; r < 4; ++r) {
      int node = node_base + r;
      if (node >= N_NODES) continue;
      float v = acc[b][r];
      if (n < 100) {
        Zrel[(size_t)node * 100 + n] = f2bf(v);
      } else if (n < 200) {
        Zroot[(size_t)node * 100 + (n - 100)] = f2bf(v + bias_s[n - 100]);
      }
    }
  }
}

// ---------------- gather: H[i] = relu(Zroot[i] + sum Zrel[src]) in bf16, padded to 128 ----------
// One wave per node; scalar offs/csr loads; 8-edge unroll with independent accumulators.

__global__ __launch_bounds__(256) void gather_bf16(
    const ushort_t* __restrict__ Zrel, const ushort_t* __restrict__ Zroot,
    const int* __restrict__ offs, const int* __restrict__ csr,
    ushort_t* __restrict__ H) {
  int node = blockIdx.x * 4 + (threadIdx.x >> 6);
  node = __builtin_amdgcn_readfirstlane(node);  // force wave-uniform -> scalar loads
  int lane = threadIdx.x & 63;
  int off = (lane < 50 ? lane : 49) * 2;  // ushort offset within 100-col row

  uint_t z = *(const uint_t*)(Zroot + (size_t)node * 100 + off);
  float p0[8], p1[8];
#pragma unroll
  for (int u = 0; u < 8; ++u) { p0[u] = 0.f; p1[u] = 0.f; }
  p0[0] = __uint_as_float(z << 16);
  p1[0] = __uint_as_float(z & 0xffff0000u);

  int s = offs[node], e = offs[node + 1];
  int j = s;
  for (; j + 7 < e; j += 8) {
    uint_t zz[8];
#pragma unroll
    for (int u = 0; u < 8; ++u) {
      int idx = csr[j + u];
      zz[u] = *(const uint_t*)(Zrel + (size_t)idx * 100 + off);
    }
#pragma unroll
    for (int u = 0; u < 8; ++u) {
      p0[u] += __uint_as_float(zz[u] << 16);
      p1[u] += __uint_as_float(zz[u] & 0xffff0000u);
    }
  }
  for (; j < e; ++j) {
    int idx = csr[j];
    uint_t z0 = *(const uint_t*)(Zrel + (size_t)idx * 100 + off);
    p0[0] += __uint_as_float(z0 << 16);
    p1[0] += __uint_as_float(z0 & 0xffff0000u);
  }
  float a0 = ((p0[0] + p0[1]) + (p0[2] + p0[3])) + ((p0[4] + p0[5]) + (p0[6] + p0[7]));
  float a1 = ((p1[0] + p1[1]) + (p1[2] + p1[3])) + ((p1[4] + p1[5]) + (p1[6] + p1[7]));
  a0 = fmaxf(a0, 0.f);
  a1 = fmaxf(a1, 0.f);
  uint_t outp = (uint_t)f2bf(a0) | ((uint_t)f2bf(a1) << 16);
  if (lane >= 50) outp = 0u;  // pad cols 100..127 = 0
  *(uint_t*)(H + (size_t)node * 128 + lane * 2) = outp;
}

// ---------------- global mean pool: 1 block/graph, 16 node-rows x 64 lanes ----------------

__global__ __launch_bounds__(1024) void pool_kernel(const ushort_t* __restrict__ H,
                                                    const int* __restrict__ batch,
                                                    float* __restrict__ pooled) {
  int g = blockIdx.x;
  int t = threadIdx.x;
  int lo = 0, hi = N_NODES;
  while (lo < hi) { int mid = (lo + hi) >> 1; if (batch[mid] < g) lo = mid + 1; else hi = mid; }
  int s = lo;
  hi = N_NODES;
  while (lo < hi) { int mid = (lo + hi) >> 1; if (batch[mid] <= g) lo = mid + 1; else hi = mid; }
  int e = lo;

  int row = t >> 6;      // 16 node-rows
  int lane = t & 63;
  int off = (lane < 50 ? lane : 49) * 2;
  float a0 = 0.f, a1 = 0.f;
  for (int n = s + row; n < e; n += 16) {
    uint_t z = *(const uint_t*)(H + (size_t)n * 128 + off);
    a0 += __uint_as_float(z << 16);
    a1 += __uint_as_float(z & 0xffff0000u);
  }
  __shared__ float sh[16][104];
  if (lane < 50) { sh[row][lane * 2] = a0; sh[row][lane * 2 + 1] = a1; }
  __syncthreads();
  if (t < 100) {
    float acc = 0.f;
#pragma unroll
    for (int r = 0; r < 16; ++r) acc += sh[r][t];
    int cnt = e - s;
    float d = (cnt > 0) ? (float)cnt : 1.f;
    pooled[(size_t)g * F + t] = acc / d;
  }
}

// ---------------- fused 3-layer MLP head (fp32) ----------------

__global__ void mlp_kernel(const float* __restrict__ pooled,
                           const float* __restrict__ lw1, const float* __restrict__ lb1,
                           const float* __restrict__ lw2, const float* __restrict__ lb2,
                           const float* __restrict__ lw3, const float* __restrict__ lb3,
                           float* __restrict__ out) {
  int g = blockIdx.x;
  int t = threadIdx.x;
  __shared__ float r0[F], r1[F], r2[F];
  if (t < F) r0[t] = pooled[(size_t)g * F + t];
  __syncthreads();
  if (t < F) {
    float s = lb1[t];
    for (int k = 0; k < F; ++k) s += r0[k] * lw1[t * F + k];
    r1[t] = fmaxf(s, 0.f);
  }
  __syncthreads();
  if (t < F) {
    float s = lb2[t];
    for (int k = 0; k < F; ++k) s += r1[k] * lw2[t * F + k];
    r2[t] = fmaxf(s, 0.f);
  }
  __syncthreads();
  if (t < 29) {
    float s = lb3[t];
    for (int k = 0; k < F; ++k) s += r2[k] * lw3[t * F + k];
    out[g * 29 + t] = s;
  }
}

// ---------------- launch ------------------------------------------------------------------------

extern "C" void kernel_launch(void* const* d_in, const int* in_sizes, int n_in,
                              void* d_out, int out_size, void* d_ws, size_t ws_size,
                              hipStream_t stream) {
  const float* x       = (const float*)d_in[0];
  const int*   ei      = (const int*)d_in[1];
  const int*   batch   = (const int*)d_in[2];
  const float* w1_rel  = (const float*)d_in[3];
  const float* w1_root = (const float*)d_in[4];
  const float* b1      = (const float*)d_in[5];
  const float* w_rel   = (const float*)d_in[6];
  const float* w_root  = (const float*)d_in[7];
  const float* bvec    = (const float*)d_in[8];
  const float* lw1     = (const float*)d_in[9];
  const float* lb1     = (const float*)d_in[10];
  const float* lw2     = (const float*)d_in[11];
  const float* lb2     = (const float*)d_in[12];
  const float* lw3     = (const float*)d_in[13];
  const float* lb3     = (const float*)d_in[14];
  float* out = (float*)d_out;

  // workspace layout
  char* ws = (char*)d_ws;
  size_t o = 0;
  auto alloc = [&](size_t bytes) { void* p = ws + o; o = (o + bytes + 511) & ~(size_t)511; return p; };
  ushort_t* H    = (ushort_t*)alloc((size_t)N_NODES * 128 * 2);   // 12.8 MB
  ushort_t* Zrel = (ushort_t*)alloc((size_t)N_NODES * 100 * 2);   // 10 MB
  ushort_t* Zroot= (ushort_t*)alloc((size_t)N_NODES * 100 * 2);   // 10 MB
  ushort_t* Wp1  = (ushort_t*)alloc((size_t)208 * 352 * 2);
  ushort_t* Wp   = (ushort_t*)alloc((size_t)4 * 208 * 128 * 2);
  float*    pooled = (float*)alloc((size_t)N_GRAPHS * F * 4);
  int* cnt    = (int*)alloc((size_t)SCAN_PAD * 4);
  int* excl   = (int*)alloc((size_t)SCAN_PAD * 4);
  int* bsum   = (int*)alloc((size_t)128 * 4);
  int* offs   = (int*)alloc((size_t)(N_NODES + 1) * 4);
  int* cursor = (int*)alloc((size_t)(N_NODES + 1) * 4);
  int* csr    = (int*)alloc((size_t)N_EDGES * 4);

  const int E = N_EDGES;
  const int* srcv = ei;
  const int* dstv = ei + E;

  int nchunk = (E + FILL_CHUNK - 1) / FILL_CHUNK;  // 391
  // CSR build (parallel 3-phase scan; hist/fill dst-partitioned 8-way)
  hipMemsetAsync(cnt, 0, (size_t)SCAN_PAD * sizeof(int), stream);
  hist_kernel<<<nchunk * 8, 256, 0, stream>>>(dstv, cnt, E);
  scan1_kernel<<<SCAN_NB, SCAN_B, 0, stream>>>(cnt, excl, bsum);
  scan2_kernel<<<1, 128, 0, stream>>>(bsum);
  scan3_kernel<<<SCAN_NB, SCAN_B, 0, stream>>>(excl, bsum, offs, cursor);
  fill_kernel<<<nchunk * 8, 256, 0, stream>>>(srcv, dstv, cursor, csr, E);

  // weight packing
  pack_w1_kernel<<<208, 128, 0, stream>>>(w1_rel, w1_root, Wp1);
  pack_w_kernel<<<dim3(208, 4), 128, 0, stream>>>(w_rel, w_root, Wp);

  int mmgrid = (N_NODES + 63) / 64;  // 782
  // layer 1: A = x fp32 [50000][336], Kp=352
  conv_mfma<true><<<mmgrid, 256, 0, stream>>>(x, Wp1, b1, Zrel, Zroot, 352);
  gather_bf16<<<N_NODES / 4, 256, 0, stream>>>(Zrel, Zroot, offs, csr, H);
  // layers 2..5: A = H bf16 [50000][128], Kp=128
  for (int l = 0; l < 4; ++l) {
    conv_mfma<false><<<mmgrid, 256, 0, stream>>>(H, Wp + (size_t)l * 208 * 128,
                                                 bvec + (size_t)l * F, Zrel, Zroot, 128);
    gather_bf16<<<N_NODES / 4, 256, 0, stream>>>(Zrel, Zroot, offs, csr, H);
  }
  pool_kernel<<<N_GRAPHS, 1024, 0, stream>>>(H, batch, pooled);
  mlp_kernel<<<N_GRAPHS, 128, 0, stream>>>(pooled, lw1, lb1, lw2, lb2, lw3, lb3, out);
}

// Round 7
// 468.297 us; speedup vs baseline: 2.7461x; 1.0159x over previous
//
#include <hip/hip_runtime.h>

#define N_NODES 50000
#define N_EDGES 800000
#define N_GRAPHS 256
#define F 100  // hidden dim

#define SCAN_B 512
#define SCAN_NB 98          // 98*512 = 50176 >= 50001
#define SCAN_PAD (SCAN_NB * SCAN_B)

#define PART_SZ 6250        // 8 dst partitions * 6250 = 50000
#define FILL_CHUNK 2048

#define SROW 72             // LDS row stride in shorts (36 dwords: bank=4*(r+q)%32, even phases)

typedef __attribute__((ext_vector_type(8))) short bf16x8;
typedef __attribute__((ext_vector_type(4))) float f32x4;
typedef unsigned short ushort_t;
typedef unsigned int uint_t;

__device__ inline ushort_t f2bf(float f) {  // RNE float->bf16
  uint_t u = __float_as_uint(f);
  uint_t r = (u + 0x7fffu + ((u >> 16) & 1u)) >> 16;
  return (ushort_t)r;
}

// ---------------- CSR build (counting sort by dst, rebuilt every call) ----------------
// hist/fill dst-range partitioned by blockIdx&7 (XCD round-robin heuristic) so csr/cursor
// atomics+scatters for a dst range stay in one XCD's L2 (R4->R6: fill 55 -> ~20 us).

__global__ __launch_bounds__(256) void hist_kernel(const int* __restrict__ dst,
                                                   int* __restrict__ cnt, int E) {
  int part = blockIdx.x & 7;
  int lo = part * PART_SZ, hi = lo + PART_SZ;
  int base = (blockIdx.x >> 3) * FILL_CHUNK;
  int end = base + FILL_CHUNK; if (end > E) end = E;
  for (int i = base + threadIdx.x; i < end; i += 256) {
    int d = dst[i];
    if (d >= lo && d < hi) atomicAdd(&cnt[d], 1);
  }
}

__global__ __launch_bounds__(SCAN_B) void scan1_kernel(const int* __restrict__ cnt,
                                                       int* __restrict__ excl,
                                                       int* __restrict__ bsum) {
  __shared__ int sh[SCAN_B];
  int t = threadIdx.x;
  int i = blockIdx.x * SCAN_B + t;
  int v = cnt[i];
  sh[t] = v;
  __syncthreads();
  for (int off = 1; off < SCAN_B; off <<= 1) {
    int u = (t >= off) ? sh[t - off] : 0;
    __syncthreads();
    sh[t] += u;
    __syncthreads();
  }
  excl[i] = sh[t] - v;
  if (t == SCAN_B - 1) bsum[blockIdx.x] = sh[t];
}

__global__ __launch_bounds__(128) void scan2_kernel(int* __restrict__ bsum) {
  __shared__ int sh[128];
  int t = threadIdx.x;
  int v = (t < SCAN_NB) ? bsum[t] : 0;
  sh[t] = v;
  __syncthreads();
  for (int off = 1; off < 128; off <<= 1) {
    int u = (t >= off) ? sh[t - off] : 0;
    __syncthreads();
    sh[t] += u;
    __syncthreads();
  }
  if (t < SCAN_NB) bsum[t] = sh[t] - v;
}

__global__ __launch_bounds__(SCAN_B) void scan3_kernel(const int* __restrict__ excl,
                                                       const int* __restrict__ bsum,
                                                       int* __restrict__ offs,
                                                       int* __restrict__ cursor) {
  int i = blockIdx.x * SCAN_B + threadIdx.x;
  int v = excl[i] + bsum[blockIdx.x];
  if (i <= N_NODES) { offs[i] = v; cursor[i] = v; }
}

__global__ __launch_bounds__(256) void fill_kernel(const int* __restrict__ src,
                                                   const int* __restrict__ dst,
                                                   int* __restrict__ cursor,
                                                   int* __restrict__ csr_src, int E) {
  int part = blockIdx.x & 7;
  int lo = part * PART_SZ, hi = lo + PART_SZ;
  int base = (blockIdx.x >> 3) * FILL_CHUNK;
  int end = base + FILL_CHUNK; if (end > E) end = E;
  for (int i = base + threadIdx.x; i < end; i += 256) {
    int d = dst[i];
    if (d >= lo && d < hi) {
      int p = atomicAdd(&cursor[d], 1);
      csr_src[p] = src[i];
    }
  }
}

// ---------------- weight packing: [208][Kp] bf16, zero-padded ----------------

__global__ void pack_w1_kernel(const float* __restrict__ w1_rel, const float* __restrict__ w1_root,
                               ushort_t* __restrict__ Wp1) {
  int row = blockIdx.x;  // 208
  for (int k = threadIdx.x; k < 384; k += 128) {
    float v = 0.f;
    if (k < 336) {
      if (row < 100) v = w1_rel[row * 336 + k];
      else if (row < 200) v = w1_root[(row - 100) * 336 + k];
    }
    Wp1[(size_t)row * 384 + k] = f2bf(v);
  }
}

__global__ void pack_w_kernel(const float* __restrict__ w_rel, const float* __restrict__ w_root,
                              ushort_t* __restrict__ Wp) {
  int row = blockIdx.x;  // 208
  int l = blockIdx.y;    // 4
  int k = threadIdx.x;   // 128
  float v = 0.f;
  if (k < 100) {
    if (row < 100) v = w_rel[((size_t)l * 100 + row) * 100 + k];
    else if (row < 200) v = w_root[((size_t)l * 100 + row - 100) * 100 + k];
  }
  Wp[((size_t)l * 208 + row) * 128 + k] = f2bf(v);
}

// ---------------- MFMA conv: Zrel = A@Wrel.T (bf16), Zroot = A@Wroot.T + b ----------------
// R7: BK=64 K-chunks, register-prefetch double buffer (load chunk k+64 after the barrier
// while MFMA consumes chunk k from LDS), LDS row stride 72 shorts for even bank phases.
// Block: 256 threads = 4 waves; tile 64 nodes x 208 feats; wave w owns m-rows [16w,16w+16).
// mfma_f32_16x16x32_bf16: A[m=lane&15][k=q*8+j]; B[k=q*8+j][n=lane&15];
// D: lane,reg -> D[m=q*4+reg][n=lane&15]  (q = lane>>4)

template <bool AF32>
__global__ __launch_bounds__(256) void conv_mfma(
    const void* __restrict__ Aptr, const ushort_t* __restrict__ Wp,
    const float* __restrict__ bias,
    ushort_t* __restrict__ Zrel, ushort_t* __restrict__ Zroot, int Kp) {
  __shared__ short alds[64 * SROW];    //  9.2 KB
  __shared__ short blds[208 * SROW];   // 29.9 KB
  __shared__ float bias_s[104];

  int tid = threadIdx.x;
  int n0 = blockIdx.x * 64;
  if (tid < 100) bias_s[tid] = bias[tid];

  f32x4 acc[13];
#pragma unroll
  for (int b = 0; b < 13; ++b) acc[b] = (f32x4)0.f;

  int w = tid >> 6, lane = tid & 63, q = lane >> 4, m16 = lane & 15;

  // staging decomposition: A = 512 16B-chunks (2/thread), B = 1664 16B-chunks (<=7/thread)
  int ar[2], aq[2];
#pragma unroll
  for (int u = 0; u < 2; ++u) { int c = tid + u * 256; ar[u] = c >> 3; aq[u] = c & 7; }

  bf16x8 areg[2], breg[7];

  // ---- load chunk k0 into registers ----
  auto load_chunk = [&](int k0) {
#pragma unroll
    for (int u = 0; u < 2; ++u) {
      int node = n0 + ar[u];
      int k = k0 + aq[u] * 8;
      bf16x8 val = (bf16x8)0;
      if (AF32) {
        if (node < N_NODES && k < 336) {
          const float* p = (const float*)Aptr + (size_t)node * 336 + k;
          float4 f0 = *(const float4*)p;
          float4 f1 = *(const float4*)(p + 4);
          val[0] = (short)f2bf(f0.x); val[1] = (short)f2bf(f0.y);
          val[2] = (short)f2bf(f0.z); val[3] = (short)f2bf(f0.w);
          val[4] = (short)f2bf(f1.x); val[5] = (short)f2bf(f1.y);
          val[6] = (short)f2bf(f1.z); val[7] = (short)f2bf(f1.w);
        }
      } else {
        if (node < N_NODES)
          val = *(const bf16x8*)((const short*)Aptr + (size_t)node * 128 + k);
      }
      areg[u] = val;
    }
#pragma unroll
    for (int u = 0; u < 7; ++u) {
      int c = tid + u * 256;
      if (c < 1664) {
        int r = c >> 3, qq = c & 7;
        breg[u] = *(const bf16x8*)((const short*)Wp + (size_t)r * Kp + k0 + qq * 8);
      }
    }
  };

  load_chunk(0);

  for (int k0 = 0; k0 < Kp; k0 += 64) {
    // ---- store registers to LDS ----
#pragma unroll
    for (int u = 0; u < 2; ++u)
      *(bf16x8*)&alds[ar[u] * SROW + aq[u] * 8] = areg[u];
#pragma unroll
    for (int u = 0; u < 7; ++u) {
      int c = tid + u * 256;
      if (c < 1664) {
        int r = c >> 3, qq = c & 7;
        *(bf16x8*)&blds[r * SROW + qq * 8] = breg[u];
      }
    }
    __syncthreads();
    // ---- prefetch next chunk (overlaps with MFMA below) ----
    if (k0 + 64 < Kp) load_chunk(k0 + 64);
    // ---- compute: 2 sub-chunks of 32 K, 13 n-tiles each ----
#pragma unroll
    for (int s = 0; s < 2; ++s) {
      bf16x8 a = *(const bf16x8*)&alds[(w * 16 + m16) * SROW + s * 32 + q * 8];
#pragma unroll
      for (int b = 0; b < 13; ++b) {
        bf16x8 bf = *(const bf16x8*)&blds[(b * 16 + m16) * SROW + s * 32 + q * 8];
        acc[b] = __builtin_amdgcn_mfma_f32_16x16x32_bf16(a, bf, acc[b], 0, 0, 0);
      }
    }
    __syncthreads();
  }

  // epilogue: node = n0 + w*16 + q*4 + r ; n = b*16 + m16
  int node_base = n0 + w * 16 + q * 4;
#pragma unroll
  for (int b = 0; b < 13; ++b) {
    int n = b * 16 + m16;
#pragma unroll
    for (int r = 0; r < 4; ++r) {
      int node = node_base + r;
      if (node >= N_NODES) continue;
      float v = acc[b][r];
      if (n < 100) {
        Zrel[(size_t)node * 100 + n] = f2bf(v);
      } else if (n < 200) {
        Zroot[(size_t)node * 100 + (n - 100)] = f2bf(v + bias_s[n - 100]);
      }
    }
  }
}

// ---------------- gather: H[i] = relu(Zroot[i] + sum Zrel[src]) in bf16, padded to 128 ----------
// One wave per node; scalar offs/csr loads; 16-edge unroll -> 16 outstanding row loads.

__global__ __launch_bounds__(256) void gather_bf16(
    const ushort_t* __restrict__ Zrel, const ushort_t* __restrict__ Zroot,
    const int* __restrict__ offs, const int* __restrict__ csr,
    ushort_t* __restrict__ H) {
  int node = blockIdx.x * 4 + (threadIdx.x >> 6);
  node = __builtin_amdgcn_readfirstlane(node);  // force wave-uniform -> scalar loads
  int lane = threadIdx.x & 63;
  int off = (lane < 50 ? lane : 49) * 2;  // ushort offset within 100-col row

  uint_t z = *(const uint_t*)(Zroot + (size_t)node * 100 + off);
  float p0[8], p1[8];
#pragma unroll
  for (int u = 0; u < 8; ++u) { p0[u] = 0.f; p1[u] = 0.f; }
  p0[0] = __uint_as_float(z << 16);
  p1[0] = __uint_as_float(z & 0xffff0000u);

  int s = offs[node], e = offs[node + 1];
  int j = s;
  for (; j + 15 < e; j += 16) {
    uint_t zz[16];
#pragma unroll
    for (int u = 0; u < 16; ++u) {
      int idx = csr[j + u];
      zz[u] = *(const uint_t*)(Zrel + (size_t)idx * 100 + off);
    }
#pragma unroll
    for (int u = 0; u < 16; ++u) {
      p0[u & 7] += __uint_as_float(zz[u] << 16);
      p1[u & 7] += __uint_as_float(zz[u] & 0xffff0000u);
    }
  }
  for (; j + 3 < e; j += 4) {
    uint_t zz[4];
#pragma unroll
    for (int u = 0; u < 4; ++u) {
      int idx = csr[j + u];
      zz[u] = *(const uint_t*)(Zrel + (size_t)idx * 100 + off);
    }
#pragma unroll
    for (int u = 0; u < 4; ++u) {
      p0[u] += __uint_as_float(zz[u] << 16);
      p1[u] += __uint_as_float(zz[u] & 0xffff0000u);
    }
  }
  for (; j < e; ++j) {
    int idx = csr[j];
    uint_t z0 = *(const uint_t*)(Zrel + (size_t)idx * 100 + off);
    p0[0] += __uint_as_float(z0 << 16);
    p1[0] += __uint_as_float(z0 & 0xffff0000u);
  }
  float a0 = ((p0[0] + p0[1]) + (p0[2] + p0[3])) + ((p0[4] + p0[5]) + (p0[6] + p0[7]));
  float a1 = ((p1[0] + p1[1]) + (p1[2] + p1[3])) + ((p1[4] + p1[5]) + (p1[6] + p1[7]));
  a0 = fmaxf(a0, 0.f);
  a1 = fmaxf(a1, 0.f);
  uint_t outp = (uint_t)f2bf(a0) | ((uint_t)f2bf(a1) << 16);
  if (lane >= 50) outp = 0u;  // pad cols 100..127 = 0
  *(uint_t*)(H + (size_t)node * 128 + lane * 2) = outp;
}

// ---------------- global mean pool: 1 block/graph, 16 node-rows x 64 lanes ----------------

__global__ __launch_bounds__(1024) void pool_kernel(const ushort_t* __restrict__ H,
                                                    const int* __restrict__ batch,
                                                    float* __restrict__ pooled) {
  int g = blockIdx.x;
  int t = threadIdx.x;
  int lo = 0, hi = N_NODES;
  while (lo < hi) { int mid = (lo + hi) >> 1; if (batch[mid] < g) lo = mid + 1; else hi = mid; }
  int s = lo;
  hi = N_NODES;
  while (lo < hi) { int mid = (lo + hi) >> 1; if (batch[mid] <= g) lo = mid + 1; else hi = mid; }
  int e = lo;

  int row = t >> 6;      // 16 node-rows
  int lane = t & 63;
  int off = (lane < 50 ? lane : 49) * 2;
  float a0 = 0.f, a1 = 0.f;
  for (int n = s + row; n < e; n += 16) {
    uint_t z = *(const uint_t*)(H + (size_t)n * 128 + off);
    a0 += __uint_as_float(z << 16);
    a1 += __uint_as_float(z & 0xffff0000u);
  }
  __shared__ float sh[16][104];
  if (lane < 50) { sh[row][lane * 2] = a0; sh[row][lane * 2 + 1] = a1; }
  __syncthreads();
  if (t < 100) {
    float acc = 0.f;
#pragma unroll
    for (int r = 0; r < 16; ++r) acc += sh[r][t];
    int cnt = e - s;
    float d = (cnt > 0) ? (float)cnt : 1.f;
    pooled[(size_t)g * F + t] = acc / d;
  }
}

// ---------------- fused 3-layer MLP head (fp32) ----------------

__global__ void mlp_kernel(const float* __restrict__ pooled,
                           const float* __restrict__ lw1, const float* __restrict__ lb1,
                           const float* __restrict__ lw2, const float* __restrict__ lb2,
                           const float* __restrict__ lw3, const float* __restrict__ lb3,
                           float* __restrict__ out) {
  int g = blockIdx.x;
  int t = threadIdx.x;
  __shared__ float r0[F], r1[F], r2[F];
  if (t < F) r0[t] = pooled[(size_t)g * F + t];
  __syncthreads();
  if (t < F) {
    float s = lb1[t];
    for (int k = 0; k < F; ++k) s += r0[k] * lw1[t * F + k];
    r1[t] = fmaxf(s, 0.f);
  }
  __syncthreads();
  if (t < F) {
    float s = lb2[t];
    for (int k = 0; k < F; ++k) s += r1[k] * lw2[t * F + k];
    r2[t] = fmaxf(s, 0.f);
  }
  __syncthreads();
  if (t < 29) {
    float s = lb3[t];
    for (int k = 0; k < F; ++k) s += r2[k] * lw3[t * F + k];
    out[g * 29 + t] = s;
  }
}

// ---------------- launch ------------------------------------------------------------------------

extern "C" void kernel_launch(void* const* d_in, const int* in_sizes, int n_in,
                              void* d_out, int out_size, void* d_ws, size_t ws_size,
                              hipStream_t stream) {
  const float* x       = (const float*)d_in[0];
  const int*   ei      = (const int*)d_in[1];
  const int*   batch   = (const int*)d_in[2];
  const float* w1_rel  = (const float*)d_in[3];
  const float* w1_root = (const float*)d_in[4];
  const float* b1      = (const float*)d_in[5];
  const float* w_rel   = (const float*)d_in[6];
  const float* w_root  = (const float*)d_in[7];
  const float* bvec    = (const float*)d_in[8];
  const float* lw1     = (const float*)d_in[9];
  const float* lb1     = (const float*)d_in[10];
  const float* lw2     = (const float*)d_in[11];
  const float* lb2     = (const float*)d_in[12];
  const float* lw3     = (const float*)d_in[13];
  const float* lb3     = (const float*)d_in[14];
  float* out = (float*)d_out;

  // workspace layout
  char* ws = (char*)d_ws;
  size_t o = 0;
  auto alloc = [&](size_t bytes) { void* p = ws + o; o = (o + bytes + 511) & ~(size_t)511; return p; };
  ushort_t* H    = (ushort_t*)alloc((size_t)N_NODES * 128 * 2);   // 12.8 MB
  ushort_t* Zrel = (ushort_t*)alloc((size_t)N_NODES * 100 * 2);   // 10 MB
  ushort_t* Zroot= (ushort_t*)alloc((size_t)N_NODES * 100 * 2);   // 10 MB
  ushort_t* Wp1  = (ushort_t*)alloc((size_t)208 * 384 * 2);
  ushort_t* Wp   = (ushort_t*)alloc((size_t)4 * 208 * 128 * 2);
  float*    pooled = (float*)alloc((size_t)N_GRAPHS * F * 4);
  int* cnt    = (int*)alloc((size_t)SCAN_PAD * 4);
  int* excl   = (int*)alloc((size_t)SCAN_PAD * 4);
  int* bsum   = (int*)alloc((size_t)128 * 4);
  int* offs   = (int*)alloc((size_t)(N_NODES + 1) * 4);
  int* cursor = (int*)alloc((size_t)(N_NODES + 1) * 4);
  int* csr    = (int*)alloc((size_t)N_EDGES * 4);

  const int E = N_EDGES;
  const int* srcv = ei;
  const int* dstv = ei + E;

  int nchunk = (E + FILL_CHUNK - 1) / FILL_CHUNK;  // 391
  // CSR build (parallel 3-phase scan; hist/fill dst-partitioned 8-way)
  hipMemsetAsync(cnt, 0, (size_t)SCAN_PAD * sizeof(int), stream);
  hist_kernel<<<nchunk * 8, 256, 0, stream>>>(dstv, cnt, E);
  scan1_kernel<<<SCAN_NB, SCAN_B, 0, stream>>>(cnt, excl, bsum);
  scan2_kernel<<<1, 128, 0, stream>>>(bsum);
  scan3_kernel<<<SCAN_NB, SCAN_B, 0, stream>>>(excl, bsum, offs, cursor);
  fill_kernel<<<nchunk * 8, 256, 0, stream>>>(srcv, dstv, cursor, csr, E);

  // weight packing
  pack_w1_kernel<<<208, 128, 0, stream>>>(w1_rel, w1_root, Wp1);
  pack_w_kernel<<<dim3(208, 4), 128, 0, stream>>>(w_rel, w_root, Wp);

  int mmgrid = (N_NODES + 63) / 64;  // 782
  // layer 1: A = x fp32 [50000][336], Kp=384 (padded)
  conv_mfma<true><<<mmgrid, 256, 0, stream>>>(x, Wp1, b1, Zrel, Zroot, 384);
  gather_bf16<<<N_NODES / 4, 256, 0, stream>>>(Zrel, Zroot, offs, csr, H);
  // layers 2..5: A = H bf16 [50000][128], Kp=128
  for (int l = 0; l < 4; ++l) {
    conv_mfma<false><<<mmgrid, 256, 0, stream>>>(H, Wp + (size_t)l * 208 * 128,
                                                 bvec + (size_t)l * F, Zrel, Zroot, 128);
    gather_bf16<<<N_NODES / 4, 256, 0, stream>>>(Zrel, Zroot, offs, csr, H);
  }
  pool_kernel<<<N_GRAPHS, 1024, 0, stream>>>(H, batch, pooled);
  mlp_kernel<<<N_GRAPHS, 128, 0, stream>>>(pooled, lw1, lb1, lw2, lb2, lw3, lb3, out);
}

// Round 8
// 459.330 us; speedup vs baseline: 2.7997x; 1.0195x over previous
//
#include <hip/hip_runtime.h>

#define N_NODES 50000
#define N_EDGES 800000
#define N_GRAPHS 256
#define F 100  // hidden dim

#define SCAN_B 512
#define SCAN_NB 98          // 98*512 = 50176 >= 50001
#define SCAN_PAD (SCAN_NB * SCAN_B)

#define PART_SZ 6250        // 8 dst partitions * 6250 = 50000
#define FILL_CHUNK 2048

#define SROW 72             // LDS row stride in shorts

typedef __attribute__((ext_vector_type(8))) short bf16x8;
typedef __attribute__((ext_vector_type(4))) float f32x4;
typedef unsigned short ushort_t;
typedef unsigned int uint_t;

__device__ inline ushort_t f2bf(float f) {  // RNE float->bf16
  uint_t u = __float_as_uint(f);
  uint_t r = (u + 0x7fffu + ((u >> 16) & 1u)) >> 16;
  return (ushort_t)r;
}

// ---------------- CSR build (counting sort by dst, rebuilt every call) ----------------
// hist/fill dst-range partitioned by blockIdx&7 (XCD round-robin heuristic) so csr/cursor
// atomics+scatters for a dst range stay in one XCD's L2 (R4->R6: fill 55 -> ~20 us).

__global__ __launch_bounds__(256) void hist_kernel(const int* __restrict__ dst,
                                                   int* __restrict__ cnt, int E) {
  int part = blockIdx.x & 7;
  int lo = part * PART_SZ, hi = lo + PART_SZ;
  int base = (blockIdx.x >> 3) * FILL_CHUNK;
  int end = base + FILL_CHUNK; if (end > E) end = E;
  for (int i = base + threadIdx.x; i < end; i += 256) {
    int d = dst[i];
    if (d >= lo && d < hi) atomicAdd(&cnt[d], 1);
  }
}

__global__ __launch_bounds__(SCAN_B) void scan1_kernel(const int* __restrict__ cnt,
                                                       int* __restrict__ excl,
                                                       int* __restrict__ bsum) {
  __shared__ int sh[SCAN_B];
  int t = threadIdx.x;
  int i = blockIdx.x * SCAN_B + t;
  int v = cnt[i];
  sh[t] = v;
  __syncthreads();
  for (int off = 1; off < SCAN_B; off <<= 1) {
    int u = (t >= off) ? sh[t - off] : 0;
    __syncthreads();
    sh[t] += u;
    __syncthreads();
  }
  excl[i] = sh[t] - v;
  if (t == SCAN_B - 1) bsum[blockIdx.x] = sh[t];
}

__global__ __launch_bounds__(128) void scan2_kernel(int* __restrict__ bsum) {
  __shared__ int sh[128];
  int t = threadIdx.x;
  int v = (t < SCAN_NB) ? bsum[t] : 0;
  sh[t] = v;
  __syncthreads();
  for (int off = 1; off < 128; off <<= 1) {
    int u = (t >= off) ? sh[t - off] : 0;
    __syncthreads();
    sh[t] += u;
    __syncthreads();
  }
  if (t < SCAN_NB) bsum[t] = sh[t] - v;
}

__global__ __launch_bounds__(SCAN_B) void scan3_kernel(const int* __restrict__ excl,
                                                       const int* __restrict__ bsum,
                                                       int* __restrict__ offs,
                                                       int* __restrict__ cursor) {
  int i = blockIdx.x * SCAN_B + threadIdx.x;
  int v = excl[i] + bsum[blockIdx.x];
  if (i <= N_NODES) { offs[i] = v; cursor[i] = v; }
}

__global__ __launch_bounds__(256) void fill_kernel(const int* __restrict__ src,
                                                   const int* __restrict__ dst,
                                                   int* __restrict__ cursor,
                                                   int* __restrict__ csr_src, int E) {
  int part = blockIdx.x & 7;
  int lo = part * PART_SZ, hi = lo + PART_SZ;
  int base = (blockIdx.x >> 3) * FILL_CHUNK;
  int end = base + FILL_CHUNK; if (end > E) end = E;
  for (int i = base + threadIdx.x; i < end; i += 256) {
    int d = dst[i];
    if (d >= lo && d < hi) {
      int p = atomicAdd(&cursor[d], 1);
      csr_src[p] = src[i];
    }
  }
}

// ---------------- weight packing: [208][Kp] bf16, zero-padded ----------------

__global__ void pack_w1_kernel(const float* __restrict__ w1_rel, const float* __restrict__ w1_root,
                               ushort_t* __restrict__ Wp1) {
  int row = blockIdx.x;  // 208
  for (int k = threadIdx.x; k < 384; k += 128) {
    float v = 0.f;
    if (k < 336) {
      if (row < 100) v = w1_rel[row * 336 + k];
      else if (row < 200) v = w1_root[(row - 100) * 336 + k];
    }
    Wp1[(size_t)row * 384 + k] = f2bf(v);
  }
}

__global__ void pack_w_kernel(const float* __restrict__ w_rel, const float* __restrict__ w_root,
                              ushort_t* __restrict__ Wp) {
  int row = blockIdx.x;  // 208
  int l = blockIdx.y;    // 4
  int k = threadIdx.x;   // 128
  float v = 0.f;
  if (k < 100) {
    if (row < 100) v = w_rel[((size_t)l * 100 + row) * 100 + k];
    else if (row < 200) v = w_root[((size_t)l * 100 + row - 100) * 100 + k];
  }
  Wp[((size_t)l * 208 + row) * 128 + k] = f2bf(v);
}

// ---------------- MFMA conv: Zrel = A@Wrel.T (bf16), Zroot = A@Wroot.T + b ----------------
// R7 structure kept (BK=64, register-prefetch double buffer, SROW=72). R6 vs R7 showed
// conv time is invariant to K-loop structure (per-block latency floor); do not churn.

template <bool AF32>
__global__ __launch_bounds__(256) void conv_mfma(
    const void* __restrict__ Aptr, const ushort_t* __restrict__ Wp,
    const float* __restrict__ bias,
    ushort_t* __restrict__ Zrel, ushort_t* __restrict__ Zroot, int Kp) {
  __shared__ short alds[64 * SROW];
  __shared__ short blds[208 * SROW];
  __shared__ float bias_s[104];

  int tid = threadIdx.x;
  int n0 = blockIdx.x * 64;
  if (tid < 100) bias_s[tid] = bias[tid];

  f32x4 acc[13];
#pragma unroll
  for (int b = 0; b < 13; ++b) acc[b] = (f32x4)0.f;

  int w = tid >> 6, lane = tid & 63, q = lane >> 4, m16 = lane & 15;

  int ar[2], aq[2];
#pragma unroll
  for (int u = 0; u < 2; ++u) { int c = tid + u * 256; ar[u] = c >> 3; aq[u] = c & 7; }

  bf16x8 areg[2], breg[7];

  auto load_chunk = [&](int k0) {
#pragma unroll
    for (int u = 0; u < 2; ++u) {
      int node = n0 + ar[u];
      int k = k0 + aq[u] * 8;
      bf16x8 val = (bf16x8)0;
      if (AF32) {
        if (node < N_NODES && k < 336) {
          const float* p = (const float*)Aptr + (size_t)node * 336 + k;
          float4 f0 = *(const float4*)p;
          float4 f1 = *(const float4*)(p + 4);
          val[0] = (short)f2bf(f0.x); val[1] = (short)f2bf(f0.y);
          val[2] = (short)f2bf(f0.z); val[3] = (short)f2bf(f0.w);
          val[4] = (short)f2bf(f1.x); val[5] = (short)f2bf(f1.y);
          val[6] = (short)f2bf(f1.z); val[7] = (short)f2bf(f1.w);
        }
      } else {
        if (node < N_NODES)
          val = *(const bf16x8*)((const short*)Aptr + (size_t)node * 128 + k);
      }
      areg[u] = val;
    }
#pragma unroll
    for (int u = 0; u < 7; ++u) {
      int c = tid + u * 256;
      if (c < 1664) {
        int r = c >> 3, qq = c & 7;
        breg[u] = *(const bf16x8*)((const short*)Wp + (size_t)r * Kp + k0 + qq * 8);
      }
    }
  };

  load_chunk(0);

  for (int k0 = 0; k0 < Kp; k0 += 64) {
#pragma unroll
    for (int u = 0; u < 2; ++u)
      *(bf16x8*)&alds[ar[u] * SROW + aq[u] * 8] = areg[u];
#pragma unroll
    for (int u = 0; u < 7; ++u) {
      int c = tid + u * 256;
      if (c < 1664) {
        int r = c >> 3, qq = c & 7;
        *(bf16x8*)&blds[r * SROW + qq * 8] = breg[u];
      }
    }
    __syncthreads();
    if (k0 + 64 < Kp) load_chunk(k0 + 64);
#pragma unroll
    for (int s = 0; s < 2; ++s) {
      bf16x8 a = *(const bf16x8*)&alds[(w * 16 + m16) * SROW + s * 32 + q * 8];
#pragma unroll
      for (int b = 0; b < 13; ++b) {
        bf16x8 bf = *(const bf16x8*)&blds[(b * 16 + m16) * SROW + s * 32 + q * 8];
        acc[b] = __builtin_amdgcn_mfma_f32_16x16x32_bf16(a, bf, acc[b], 0, 0, 0);
      }
    }
    __syncthreads();
  }

  int node_base = n0 + w * 16 + q * 4;
#pragma unroll
  for (int b = 0; b < 13; ++b) {
    int n = b * 16 + m16;
#pragma unroll
    for (int r = 0; r < 4; ++r) {
      int node = node_base + r;
      if (node >= N_NODES) continue;
      float v = acc[b][r];
      if (n < 100) {
        Zrel[(size_t)node * 100 + n] = f2bf(v);
      } else if (n < 200) {
        Zroot[(size_t)node * 100 + (n - 100)] = f2bf(v + bias_s[n - 100]);
      }
    }
  }
}

// ---------------- gather: H[i] = relu(Zroot[i] + sum Zrel[src]) in bf16, padded to 128 ----------
// R8: kill the dependent-scalar-chain. One coalesced VECTOR load grabs up to 64 csr
// indices; v_readlane broadcasts each (VALU, no memory) -> all row loads independent,
// issued in groups of 8 with separate accumulators. Old form serialized ~600 cyc/edge
// on s_load(csr)->load(row) chains in the remainder ladder.

__global__ __launch_bounds__(256) void gather_bf16(
    const ushort_t* __restrict__ Zrel, const ushort_t* __restrict__ Zroot,
    const int* __restrict__ offs, const int* __restrict__ csr,
    ushort_t* __restrict__ H) {
  int node = blockIdx.x * 4 + (threadIdx.x >> 6);
  node = __builtin_amdgcn_readfirstlane(node);  // wave-uniform -> scalar offs loads
  int lane = threadIdx.x & 63;
  int off = (lane < 50 ? lane : 49) * 2;  // ushort offset within 100-col row

  uint_t z = *(const uint_t*)(Zroot + (size_t)node * 100 + off);
  float p0[8], p1[8];
#pragma unroll
  for (int u = 0; u < 8; ++u) { p0[u] = 0.f; p1[u] = 0.f; }
  p0[0] = __uint_as_float(z << 16);
  p1[0] = __uint_as_float(z & 0xffff0000u);

  int s = offs[node], e = offs[node + 1];
  for (int j = s; j < e; j += 64) {
    int take = e - j; if (take > 64) take = 64;
    int vidx = (lane < take) ? csr[j + lane] : 0;  // one coalesced 256B vector load
    int u = 0;
    for (; u + 8 <= take; u += 8) {
      uint_t zz[8];
#pragma unroll
      for (int t = 0; t < 8; ++t) {
        int idx = __builtin_amdgcn_readlane(vidx, u + t);
        zz[t] = *(const uint_t*)(Zrel + (size_t)idx * 100 + off);
      }
#pragma unroll
      for (int t = 0; t < 8; ++t) {
        p0[t] += __uint_as_float(zz[t] << 16);
        p1[t] += __uint_as_float(zz[t] & 0xffff0000u);
      }
    }
    int cnt = take - u;  // 0..7, wave-uniform
    if (cnt > 0) {
      uint_t zz[7];
#pragma unroll
      for (int t = 0; t < 7; ++t) {
        if (t < cnt) {
          int idx = __builtin_amdgcn_readlane(vidx, u + t);
          zz[t] = *(const uint_t*)(Zrel + (size_t)idx * 100 + off);
        }
      }
#pragma unroll
      for (int t = 0; t < 7; ++t) {
        if (t < cnt) {
          p0[t] += __uint_as_float(zz[t] << 16);
          p1[t] += __uint_as_float(zz[t] & 0xffff0000u);
        }
      }
    }
  }
  float a0 = ((p0[0] + p0[1]) + (p0[2] + p0[3])) + ((p0[4] + p0[5]) + (p0[6] + p0[7]));
  float a1 = ((p1[0] + p1[1]) + (p1[2] + p1[3])) + ((p1[4] + p1[5]) + (p1[6] + p1[7]));
  a0 = fmaxf(a0, 0.f);
  a1 = fmaxf(a1, 0.f);
  uint_t outp = (uint_t)f2bf(a0) | ((uint_t)f2bf(a1) << 16);
  if (lane >= 50) outp = 0u;  // pad cols 100..127 = 0
  *(uint_t*)(H + (size_t)node * 128 + lane * 2) = outp;
}

// ---------------- global mean pool: 1 block/graph, 16 node-rows x 64 lanes ----------------

__global__ __launch_bounds__(1024) void pool_kernel(const ushort_t* __restrict__ H,
                                                    const int* __restrict__ batch,
                                                    float* __restrict__ pooled) {
  int g = blockIdx.x;
  int t = threadIdx.x;
  int lo = 0, hi = N_NODES;
  while (lo < hi) { int mid = (lo + hi) >> 1; if (batch[mid] < g) lo = mid + 1; else hi = mid; }
  int s = lo;
  hi = N_NODES;
  while (lo < hi) { int mid = (lo + hi) >> 1; if (batch[mid] <= g) lo = mid + 1; else hi = mid; }
  int e = lo;

  int row = t >> 6;      // 16 node-rows
  int lane = t & 63;
  int off = (lane < 50 ? lane : 49) * 2;
  float a0 = 0.f, a1 = 0.f;
  for (int n = s + row; n < e; n += 16) {
    uint_t z = *(const uint_t*)(H + (size_t)n * 128 + off);
    a0 += __uint_as_float(z << 16);
    a1 += __uint_as_float(z & 0xffff0000u);
  }
  __shared__ float sh[16][104];
  if (lane < 50) { sh[row][lane * 2] = a0; sh[row][lane * 2 + 1] = a1; }
  __syncthreads();
  if (t < 100) {
    float acc = 0.f;
#pragma unroll
    for (int r = 0; r < 16; ++r) acc += sh[r][t];
    int cnt = e - s;
    float d = (cnt > 0) ? (float)cnt : 1.f;
    pooled[(size_t)g * F + t] = acc / d;
  }
}

// ---------------- fused 3-layer MLP head (fp32) ----------------

__global__ void mlp_kernel(const float* __restrict__ pooled,
                           const float* __restrict__ lw1, const float* __restrict__ lb1,
                           const float* __restrict__ lw2, const float* __restrict__ lb2,
                           const float* __restrict__ lw3, const float* __restrict__ lb3,
                           float* __restrict__ out) {
  int g = blockIdx.x;
  int t = threadIdx.x;
  __shared__ float r0[F], r1[F], r2[F];
  if (t < F) r0[t] = pooled[(size_t)g * F + t];
  __syncthreads();
  if (t < F) {
    float s = lb1[t];
    for (int k = 0; k < F; ++k) s += r0[k] * lw1[t * F + k];
    r1[t] = fmaxf(s, 0.f);
  }
  __syncthreads();
  if (t < F) {
    float s = lb2[t];
    for (int k = 0; k < F; ++k) s += r1[k] * lw2[t * F + k];
    r2[t] = fmaxf(s, 0.f);
  }
  __syncthreads();
  if (t < 29) {
    float s = lb3[t];
    for (int k = 0; k < F; ++k) s += r2[k] * lw3[t * F + k];
    out[g * 29 + t] = s;
  }
}

// ---------------- launch ------------------------------------------------------------------------

extern "C" void kernel_launch(void* const* d_in, const int* in_sizes, int n_in,
                              void* d_out, int out_size, void* d_ws, size_t ws_size,
                              hipStream_t stream) {
  const float* x       = (const float*)d_in[0];
  const int*   ei      = (const int*)d_in[1];
  const int*   batch   = (const int*)d_in[2];
  const float* w1_rel  = (const float*)d_in[3];
  const float* w1_root = (const float*)d_in[4];
  const float* b1      = (const float*)d_in[5];
  const float* w_rel   = (const float*)d_in[6];
  const float* w_root  = (const float*)d_in[7];
  const float* bvec    = (const float*)d_in[8];
  const float* lw1     = (const float*)d_in[9];
  const float* lb1     = (const float*)d_in[10];
  const float* lw2     = (const float*)d_in[11];
  const float* lb2     = (const float*)d_in[12];
  const float* lw3     = (const float*)d_in[13];
  const float* lb3     = (const float*)d_in[14];
  float* out = (float*)d_out;

  // workspace layout
  char* ws = (char*)d_ws;
  size_t o = 0;
  auto alloc = [&](size_t bytes) { void* p = ws + o; o = (o + bytes + 511) & ~(size_t)511; return p; };
  ushort_t* H    = (ushort_t*)alloc((size_t)N_NODES * 128 * 2);   // 12.8 MB
  ushort_t* Zrel = (ushort_t*)alloc((size_t)N_NODES * 100 * 2);   // 10 MB
  ushort_t* Zroot= (ushort_t*)alloc((size_t)N_NODES * 100 * 2);   // 10 MB
  ushort_t* Wp1  = (ushort_t*)alloc((size_t)208 * 384 * 2);
  ushort_t* Wp   = (ushort_t*)alloc((size_t)4 * 208 * 128 * 2);
  float*    pooled = (float*)alloc((size_t)N_GRAPHS * F * 4);
  int* cnt    = (int*)alloc((size_t)SCAN_PAD * 4);
  int* excl   = (int*)alloc((size_t)SCAN_PAD * 4);
  int* bsum   = (int*)alloc((size_t)128 * 4);
  int* offs   = (int*)alloc((size_t)(N_NODES + 1) * 4);
  int* cursor = (int*)alloc((size_t)(N_NODES + 1) * 4);
  int* csr    = (int*)alloc((size_t)N_EDGES * 4);

  const int E = N_EDGES;
  const int* srcv = ei;
  const int* dstv = ei + E;

  int nchunk = (E + FILL_CHUNK - 1) / FILL_CHUNK;  // 391
  // CSR build (parallel 3-phase scan; hist/fill dst-partitioned 8-way)
  hipMemsetAsync(cnt, 0, (size_t)SCAN_PAD * sizeof(int), stream);
  hist_kernel<<<nchunk * 8, 256, 0, stream>>>(dstv, cnt, E);
  scan1_kernel<<<SCAN_NB, SCAN_B, 0, stream>>>(cnt, excl, bsum);
  scan2_kernel<<<1, 128, 0, stream>>>(bsum);
  scan3_kernel<<<SCAN_NB, SCAN_B, 0, stream>>>(excl, bsum, offs, cursor);
  fill_kernel<<<nchunk * 8, 256, 0, stream>>>(srcv, dstv, cursor, csr, E);

  // weight packing
  pack_w1_kernel<<<208, 128, 0, stream>>>(w1_rel, w1_root, Wp1);
  pack_w_kernel<<<dim3(208, 4), 128, 0, stream>>>(w_rel, w_root, Wp);

  int mmgrid = (N_NODES + 63) / 64;  // 782
  // layer 1: A = x fp32 [50000][336], Kp=384 (padded)
  conv_mfma<true><<<mmgrid, 256, 0, stream>>>(x, Wp1, b1, Zrel, Zroot, 384);
  gather_bf16<<<N_NODES / 4, 256, 0, stream>>>(Zrel, Zroot, offs, csr, H);
  // layers 2..5: A = H bf16 [50000][128], Kp=128
  for (int l = 0; l < 4; ++l) {
    conv_mfma<false><<<mmgrid, 256, 0, stream>>>(H, Wp + (size_t)l * 208 * 128,
                                                 bvec + (size_t)l * F, Zrel, Zroot, 128);
    gather_bf16<<<N_NODES / 4, 256, 0, stream>>>(Zrel, Zroot, offs, csr, H);
  }
  pool_kernel<<<N_GRAPHS, 1024, 0, stream>>>(H, batch, pooled);
  mlp_kernel<<<N_GRAPHS, 128, 0, stream>>>(pooled, lw1, lb1, lw2, lb2, lw3, lb3, out);
}